// Round 1
// baseline (1835.668 us; speedup 1.0000x reference)
//
#include <hip/hip_runtime.h>
#include <hip/hip_bf16.h>

typedef unsigned short u16;
typedef short bf16x8 __attribute__((ext_vector_type(8)));
typedef float f32x4 __attribute__((ext_vector_type(4)));

#define N_ 4096
#define D_ 3072

// ---------------- static device workspace (no d_ws dependence) -------------
__device__ __align__(256) u16  g_Gb [(size_t)N_ * D_];   // feat_gen bf16
__device__ __align__(256) u16  g_Pb [(size_t)N_ * D_];   // feat_pos bf16
__device__ __align__(256) u16  g_GbT[(size_t)D_ * N_];   // transposes for V GEMMs
__device__ __align__(256) u16  g_PbT[(size_t)D_ * N_];
__device__ __align__(256) float g_Sp[(size_t)N_ * N_];   // S_pos -> dist_pos (in place)
__device__ __align__(256) float g_Sn[(size_t)N_ * N_];   // S_neg -> dist_neg (in place)
__device__ __align__(256) u16  g_Wp [(size_t)N_ * N_];   // W_pos bf16
__device__ __align__(256) u16  g_Wn [(size_t)N_ * N_];   // W_neg bf16
__device__ __align__(256) float g_V  [(size_t)N_ * D_];  // V_tau
__device__ __align__(256) float g_Vt [(size_t)N_ * D_];  // V_total
__device__ float g_ng[N_], g_np[N_];
__device__ float g_rminp[N_], g_rminn[N_], g_cminp[N_];
__device__ float g_R [3 * N_];   // row exp-sums  -> rsqrt'ed in place
__device__ float g_Cp[3 * N_];   // col exp-sums (pos) -> rsqrt'ed
__device__ float g_Cn[3 * N_];   // col exp-sums (neg = row sums by symmetry) -> rsqrt'ed
__device__ float g_spos[3 * N_], g_sneg[3 * N_];
__device__ float g_Cpart[8 * 3 * N_];
__device__ float g_part[1024];
__device__ float g_scale[1];

// ---------------- helpers ----------------
__device__ __forceinline__ u16 f2bf(float f) {
    unsigned u = __float_as_uint(f);
    u += 0x7fffu + ((u >> 16) & 1u);
    return (u16)(u >> 16);
}

__device__ __forceinline__ float blockSum256(float v) {
    __shared__ float red[4];
#pragma unroll
    for (int s = 32; s; s >>= 1) v += __shfl_down(v, s, 64);
    int l = threadIdx.x & 63, w = threadIdx.x >> 6;
    if (l == 0) red[w] = v;
    __syncthreads();
    return red[0] + red[1] + red[2] + red[3];
}

__device__ __forceinline__ void gload16(const void* g, void* lds) {
    __builtin_amdgcn_global_load_lds(
        (const __attribute__((address_space(1))) void*)g,
        (__attribute__((address_space(3))) void*)lds, 16, 0, 0);
}

// ---------------- convert fp32 -> bf16 + row sq-norms ----------------
__global__ __launch_bounds__(256) void k_convert_norm(const float* __restrict__ X, int sel) {
    u16* Xb = sel ? g_Pb : g_Gb;
    float* nr = sel ? g_np : g_ng;
    int row = blockIdx.x;
    const float* xr = X + (size_t)row * D_;
    u16* xb = Xb + (size_t)row * D_;
    float s = 0.f;
    for (int c = threadIdx.x; c < D_; c += 256) {
        float v = xr[c];
        s += v * v;
        xb[c] = f2bf(v);
    }
    s = blockSum256(s);
    if (threadIdx.x == 0) nr[row] = s;
}

// ---------------- bf16 transpose [N_][D_] -> [D_][N_] ----------------
__global__ __launch_bounds__(256) void k_transpose(int sel) {
    const u16* in = sel ? g_Pb : g_Gb;
    u16* out = sel ? g_PbT : g_GbT;
    __shared__ u16 t[32][33];
    int c0 = blockIdx.x * 32, r0 = blockIdx.y * 32;
    int tx = threadIdx.x, ty = threadIdx.y;
#pragma unroll
    for (int k = 0; k < 32; k += 8)
        t[ty + k][tx] = in[(size_t)(r0 + ty + k) * D_ + c0 + tx];
    __syncthreads();
#pragma unroll
    for (int k = 0; k < 32; k += 8)
        out[(size_t)(c0 + ty + k) * N_ + r0 + tx] = t[tx][ty + k];
}

// ---------------- bf16 MFMA GEMM, C[M,N] = A[M,K] * B[N,K]^T ----------------
// 128x128 tile, BK=32, 4 waves (2x2), each wave 64x64 (4x4 frags of 16x16x32).
__global__ __launch_bounds__(256) void k_gemm(int sel, int M, int N, int K, int sub) {
    const u16 *A, *B;
    float* C;
    switch (sel) {
        case 0: A = g_Gb; B = g_Pb;  C = g_Sp; break;   // S_pos
        case 1: A = g_Gb; B = g_Gb;  C = g_Sn; break;   // S_neg
        case 2: A = g_Wp; B = g_PbT; C = g_V;  break;   // V  = Wp @ P
        default: A = g_Wn; B = g_GbT; C = g_V; break;   // V -= Wn @ G
    }
    __shared__ u16 lA[128 * 32];
    __shared__ u16 lB[128 * 32];
    const int tid = threadIdx.x;
    const int l = tid & 63;
    const int w = tid >> 6;
    const int wr = w >> 1, wc = w & 1;
    const int i0 = blockIdx.y * 128;
    const int j0 = blockIdx.x * 128;

    f32x4 acc[4][4] = {};

    const int lrow = l >> 2;        // row within 16-row chunk
    const int lk = (l & 3) * 8;     // k element offset within 32
    const int kg = l >> 4;          // fragment k-group 0..3
    const int fr = l & 15;          // fragment row/col

    for (int k0 = 0; k0 < K; k0 += 32) {
        __syncthreads();   // previous iteration's ds_reads done before overwrite
#pragma unroll
        for (int q = 0; q < 2; ++q) {
            int c = w + q * 4;                 // chunk 0..7, wave-uniform
            const u16* ga = A + (size_t)(i0 + c * 16 + lrow) * K + k0 + lk;
            gload16(ga, &lA[c * 512]);         // HW: uniform base + lane*16B
            const u16* gb = B + (size_t)(j0 + c * 16 + lrow) * K + k0 + lk;
            gload16(gb, &lB[c * 512]);
        }
        asm volatile("s_waitcnt vmcnt(0)" ::: "memory");
        __syncthreads();

        bf16x8 av[4], bv[4];
#pragma unroll
        for (int m = 0; m < 4; ++m)
            av[m] = *(const bf16x8*)&lA[(wr * 64 + m * 16 + fr) * 32 + kg * 8];
#pragma unroll
        for (int n = 0; n < 4; ++n)
            bv[n] = *(const bf16x8*)&lB[(wc * 64 + n * 16 + fr) * 32 + kg * 8];
#pragma unroll
        for (int m = 0; m < 4; ++m)
#pragma unroll
            for (int n = 0; n < 4; ++n)
                acc[m][n] = __builtin_amdgcn_mfma_f32_16x16x32_bf16(av[m], bv[n], acc[m][n], 0, 0, 0);
    }

    const int fq = l >> 4;
#pragma unroll
    for (int m = 0; m < 4; ++m)
#pragma unroll
        for (int n = 0; n < 4; ++n)
#pragma unroll
            for (int r = 0; r < 4; ++r) {
                int row = i0 + wr * 64 + m * 16 + fq * 4 + r;
                int col = j0 + wc * 64 + n * 16 + fr;
                size_t idx = (size_t)row * N + col;
                float v = acc[m][n][r];
                C[idx] = sub ? (C[idx] - v) : v;
            }
}

// ---------------- S -> dist (in place), diag mask for neg ----------------
__global__ __launch_bounds__(256) void k_s2dist(int sel) {
    float* Sd = sel ? g_Sn : g_Sp;
    const float* nb = sel ? g_ng : g_np;
    int i = blockIdx.y;
    int j = blockIdx.x * 256 + threadIdx.x;
    size_t idx = (size_t)i * N_ + j;
    float d2 = g_ng[i] + nb[j] - 2.f * Sd[idx];
    float d = sqrtf(fmaxf(d2, 0.f));
    if (sel && i == j) d += 1000000.0f;
    Sd[idx] = d;
}

// ---------------- row mins over both matrices ----------------
__global__ __launch_bounds__(256) void k_rowmin() {
    int i = blockIdx.x;
    const float* rp = g_Sp + (size_t)i * N_;
    const float* rn = g_Sn + (size_t)i * N_;
    float mp = 1e30f, mn = 1e30f;
    for (int j = threadIdx.x; j < N_; j += 256) {
        mp = fminf(mp, rp[j]);
        mn = fminf(mn, rn[j]);
    }
    __shared__ float red[2][4];
#pragma unroll
    for (int s = 32; s; s >>= 1) {
        mp = fminf(mp, __shfl_down(mp, s, 64));
        mn = fminf(mn, __shfl_down(mn, s, 64));
    }
    int l = threadIdx.x & 63, w = threadIdx.x >> 6;
    if (l == 0) { red[0][w] = mp; red[1][w] = mn; }
    __syncthreads();
    if (threadIdx.x == 0)
        g_rminp[i] = fminf(fminf(red[0][0], red[0][1]), fminf(red[0][2], red[0][3]));
    if (threadIdx.x == 1)
        g_rminn[i] = fminf(fminf(red[1][0], red[1][1]), fminf(red[1][2], red[1][3]));
}

// ---------------- column min of d_pos (atomicMin on uint == float min for d>=0) --
__global__ __launch_bounds__(256) void k_colmin_init() {
    g_cminp[blockIdx.x * 256 + threadIdx.x] = 1e30f;
}
__global__ __launch_bounds__(256) void k_colmin() {
    int j = blockIdx.x * 256 + threadIdx.x;
    int i0 = blockIdx.y * 512;
    float m = 1e30f;
    for (int i = i0; i < i0 + 512; ++i)
        m = fminf(m, g_Sp[(size_t)i * N_ + j]);
    atomicMin((unsigned int*)&g_cminp[j], __float_as_uint(m));
}

// ---------------- row exp-sums: R (all 8192, ref rdmin) and Cn (neg rows, ref rminn) --
__global__ __launch_bounds__(256) void k_rowexp() {
    int i = blockIdx.x;
    float rd = fminf(g_rminp[i], g_rminn[i]);
    float rn = g_rminn[i];
    const float* rp = g_Sp + (size_t)i * N_;
    const float* rng = g_Sn + (size_t)i * N_;
    float v[6] = {0, 0, 0, 0, 0, 0};
    for (int j = threadIdx.x; j < N_; j += 256) {
        float e = rd - rp[j];
        v[0] += __expf(e * 50.f);
        v[1] += __expf(e * 20.f);
        v[2] += __expf(e * 5.f);
    }
    for (int j = threadIdx.x; j < N_; j += 256) {
        float d = rng[j];
        float e = rd - d, en = rn - d;
        v[0] += __expf(e * 50.f);
        v[1] += __expf(e * 20.f);
        v[2] += __expf(e * 5.f);
        v[3] += __expf(en * 50.f);
        v[4] += __expf(en * 20.f);
        v[5] += __expf(en * 5.f);
    }
    __shared__ float red[6][4];
#pragma unroll
    for (int k = 0; k < 6; ++k)
#pragma unroll
        for (int s = 32; s; s >>= 1) v[k] += __shfl_down(v[k], s, 64);
    int l = threadIdx.x & 63, w = threadIdx.x >> 6;
    if (l == 0)
#pragma unroll
        for (int k = 0; k < 6; ++k) red[k][w] = v[k];
    __syncthreads();
    int t = threadIdx.x;
    if (t < 6) {
        float s = red[t][0] + red[t][1] + red[t][2] + red[t][3];
        if (t < 3) g_R[t * N_ + i] = s;
        else g_Cn[(t - 3) * N_ + i] = s;
    }
}

// ---------------- column exp-sums of d_pos (partials, deterministic reduce) ----
__global__ __launch_bounds__(256) void k_colexp() {
    int j = blockIdx.x * 256 + threadIdx.x;
    int ch = blockIdx.y;
    int i0 = ch * 512;
    float cm = g_cminp[j];
    float a0 = 0, a1 = 0, a2 = 0;
    for (int i = i0; i < i0 + 512; ++i) {
        float e = cm - g_Sp[(size_t)i * N_ + j];
        a0 += __expf(e * 50.f);
        a1 += __expf(e * 20.f);
        a2 += __expf(e * 5.f);
    }
    g_Cpart[(size_t)ch * (3 * N_) + 0 * N_ + j] = a0;
    g_Cpart[(size_t)ch * (3 * N_) + 1 * N_ + j] = a1;
    g_Cpart[(size_t)ch * (3 * N_) + 2 * N_ + j] = a2;
}
__global__ __launch_bounds__(256) void k_colreduce() {
    int idx = blockIdx.x * 256 + threadIdx.x;  // 0 .. 3*N_-1
    float s = 0;
#pragma unroll
    for (int ch = 0; ch < 8; ++ch) s += g_Cpart[(size_t)ch * (3 * N_) + idx];
    g_Cp[idx] = s;
}

// ---------------- in-place rsqrt of all exp-sum arrays ----------------
__global__ __launch_bounds__(256) void k_rsq_all() {
    int idx = blockIdx.x * 256 + threadIdx.x;  // 0 .. 3*N_-1
    g_R[idx] = rsqrtf(g_R[idx]);
    g_Cp[idx] = rsqrtf(g_Cp[idx]);
    g_Cn[idx] = rsqrtf(g_Cn[idx]);
}

// ---------------- row sums of A (pos and neg parts), all taus ----------------
__global__ __launch_bounds__(256) void k_rowsumA() {
    int i = blockIdx.x;
    float rd = fminf(g_rminp[i], g_rminn[i]);
    const float* rp = g_Sp + (size_t)i * N_;
    const float* rng = g_Sn + (size_t)i * N_;
    float v[6] = {0, 0, 0, 0, 0, 0};
    for (int j = threadIdx.x; j < N_; j += 256) {
        float base = 0.5f * (rd + g_cminp[j]) - rp[j];
        v[0] += __expf(base * 50.f) * g_Cp[0 * N_ + j];
        v[1] += __expf(base * 20.f) * g_Cp[1 * N_ + j];
        v[2] += __expf(base * 5.f) * g_Cp[2 * N_ + j];
    }
    for (int j = threadIdx.x; j < N_; j += 256) {
        float base = 0.5f * (rd + g_rminn[j]) - rng[j];
        v[3] += __expf(base * 50.f) * g_Cn[0 * N_ + j];
        v[4] += __expf(base * 20.f) * g_Cn[1 * N_ + j];
        v[5] += __expf(base * 5.f) * g_Cn[2 * N_ + j];
    }
    __shared__ float red[6][4];
#pragma unroll
    for (int k = 0; k < 6; ++k)
#pragma unroll
        for (int s = 32; s; s >>= 1) v[k] += __shfl_down(v[k], s, 64);
    int l = threadIdx.x & 63, w = threadIdx.x >> 6;
    if (l == 0)
#pragma unroll
        for (int k = 0; k < 6; ++k) red[k][w] = v[k];
    __syncthreads();
    int t = threadIdx.x;
    if (t < 6) {
        float s = red[t][0] + red[t][1] + red[t][2] + red[t][3];
        if (t < 3) g_spos[t * N_ + i] = s * g_R[t * N_ + i];   // g_R = 1/sqrt(R)
        else g_sneg[(t - 3) * N_ + i] = s * g_R[(t - 3) * N_ + i];
    }
}

// ---------------- W generation for one tau ----------------
__global__ __launch_bounds__(256) void k_wgen(int t, float itau) {
    int i = blockIdx.y;
    int j = blockIdx.x * 256 + threadIdx.x;
    float rd = fminf(g_rminp[i], g_rminn[i]);
    float iRi = g_R[t * N_ + i];
    float spi = g_spos[t * N_ + i];
    float sni = g_sneg[t * N_ + i];
    size_t idx = (size_t)i * N_ + j;
    float d = g_Sp[idx];
    float Ap = __expf((0.5f * (rd + g_cminp[j]) - d) * itau) * iRi * g_Cp[t * N_ + j];
    g_Wp[idx] = f2bf(Ap * sni);
    d = g_Sn[idx];
    float An = __expf((0.5f * (rd + g_rminn[j]) - d) * itau) * iRi * g_Cn[t * N_ + j];
    g_Wn[idx] = f2bf(An * spi);
}

// ---------------- sum of squares (V or Vt) ----------------
__global__ __launch_bounds__(256) void k_reduce_sq(int sel) {
    const float4* V = (const float4*)(sel ? g_Vt : g_V);
    const size_t n4 = (size_t)N_ * D_ / 4;
    float s = 0.f;
    for (size_t i = (size_t)blockIdx.x * 256 + threadIdx.x; i < n4; i += (size_t)1024 * 256) {
        float4 v = V[i];
        s += v.x * v.x + v.y * v.y + v.z * v.z + v.w * v.w;
    }
    s = blockSum256(s);
    if (threadIdx.x == 0) g_part[blockIdx.x] = s;
}

// mode 0: g_scale = rsqrt(mean + eps);  mode 1: out[0] = m/(m+eps)
__global__ __launch_bounds__(256) void k_finalize(int mode, float* out) {
    int t = threadIdx.x;
    float s = g_part[t] + g_part[t + 256] + g_part[t + 512] + g_part[t + 768];
    s = blockSum256(s);
    if (t == 0) {
        float m = s / ((float)N_ * (float)D_);
        if (mode) out[0] = m / (m + 1e-8f);
        else g_scale[0] = rsqrtf(m + 1e-8f);
    }
}

// ---------------- V_total accumulate ----------------
__global__ __launch_bounds__(256) void k_vaccum(int first) {
    float sc = g_scale[0];
    float4* Vt = (float4*)g_Vt;
    const float4* V = (const float4*)g_V;
    const size_t n4 = (size_t)N_ * D_ / 4;
    for (size_t i = (size_t)blockIdx.x * 256 + threadIdx.x; i < n4; i += (size_t)2048 * 256) {
        float4 v = V[i];
        float4 o;
        if (first) { o.x = 0; o.y = 0; o.z = 0; o.w = 0; }
        else o = Vt[i];
        o.x += v.x * sc; o.y += v.y * sc; o.z += v.z * sc; o.w += v.w * sc;
        Vt[i] = o;
    }
}

// ---------------- host orchestration ----------------
extern "C" void kernel_launch(void* const* d_in, const int* in_sizes, int n_in,
                              void* d_out, int out_size, void* d_ws, size_t ws_size,
                              hipStream_t stream) {
    const float* xg = (const float*)d_in[0];
    const float* xp = (const float*)d_in[1];
    float* out = (float*)d_out;

    k_convert_norm<<<N_, 256, 0, stream>>>(xg, 0);
    k_convert_norm<<<N_, 256, 0, stream>>>(xp, 1);
    k_transpose<<<dim3(D_ / 32, N_ / 32), dim3(32, 8), 0, stream>>>(0);
    k_transpose<<<dim3(D_ / 32, N_ / 32), dim3(32, 8), 0, stream>>>(1);

    k_gemm<<<dim3(N_ / 128, N_ / 128), 256, 0, stream>>>(0, N_, N_, D_, 0);  // S_pos
    k_gemm<<<dim3(N_ / 128, N_ / 128), 256, 0, stream>>>(1, N_, N_, D_, 0);  // S_neg

    k_s2dist<<<dim3(N_ / 256, N_), 256, 0, stream>>>(0);
    k_s2dist<<<dim3(N_ / 256, N_), 256, 0, stream>>>(1);

    k_rowmin<<<N_, 256, 0, stream>>>();
    k_colmin_init<<<N_ / 256, 256, 0, stream>>>();
    k_colmin<<<dim3(N_ / 256, 8), 256, 0, stream>>>();
    k_rowexp<<<N_, 256, 0, stream>>>();
    k_colexp<<<dim3(N_ / 256, 8), 256, 0, stream>>>();
    k_colreduce<<<3 * N_ / 256, 256, 0, stream>>>();
    k_rsq_all<<<3 * N_ / 256, 256, 0, stream>>>();
    k_rowsumA<<<N_, 256, 0, stream>>>();

    const float itau[3] = {50.f, 20.f, 5.f};
    for (int t = 0; t < 3; ++t) {
        k_wgen<<<dim3(N_ / 256, N_), 256, 0, stream>>>(t, itau[t]);
        k_gemm<<<dim3(D_ / 128, N_ / 128), 256, 0, stream>>>(2, N_, D_, N_, 0);  // V  = Wp@P
        k_gemm<<<dim3(D_ / 128, N_ / 128), 256, 0, stream>>>(3, N_, D_, N_, 1);  // V -= Wn@G
        k_reduce_sq<<<1024, 256, 0, stream>>>(0);
        k_finalize<<<1, 256, 0, stream>>>(0, out);
        k_vaccum<<<2048, 256, 0, stream>>>(t == 0 ? 1 : 0);
    }
    k_reduce_sq<<<1024, 256, 0, stream>>>(1);
    k_finalize<<<1, 256, 0, stream>>>(1, out);
}

// Round 2
// 1360.350 us; speedup vs baseline: 1.3494x; 1.3494x over previous
//
#include <hip/hip_runtime.h>
#include <hip/hip_bf16.h>

typedef unsigned short u16;
typedef short bf16x8 __attribute__((ext_vector_type(8)));
typedef float f32x4 __attribute__((ext_vector_type(4)));

#define N_ 4096
#define D_ 3072

// ---------------- static device workspace ----------------
__device__ __align__(256) u16  g_Feat[(size_t)2 * N_ * D_];      // [Gb rows 0..4095 ; Pb rows 4096..8191]
__device__ __align__(256) u16  g_BT[(size_t)(D_ + 64) * 2 * N_]; // [3072(+64 pad)][8192] = [PbT | GbT]
__device__ __align__(256) u16  g_W [(size_t)N_ * 2 * N_];        // [4096][8192] = [Wp | -Wn]
__device__ __align__(256) float g_Sp[(size_t)N_ * N_];
__device__ __align__(256) float g_Sn[(size_t)N_ * N_];
__device__ __align__(256) float g_V [(size_t)N_ * D_];
__device__ __align__(256) float g_Vt[(size_t)N_ * D_];
__device__ float g_ng[N_], g_np[N_];
__device__ float g_rminp[N_], g_rminn[N_], g_cminp[N_];
__device__ float g_R [3 * N_];
__device__ float g_Cp[3 * N_];
__device__ float g_Cn[3 * N_];
__device__ float g_spos[3 * N_], g_sneg[3 * N_];
__device__ float g_Cpart[8 * 3 * N_];
__device__ float g_part[1024];
__device__ float g_scale[1];

// ---------------- helpers ----------------
__device__ __forceinline__ u16 f2bf(float f) {
    unsigned u = __float_as_uint(f);
    u += 0x7fffu + ((u >> 16) & 1u);
    return (u16)(u >> 16);
}

__device__ __forceinline__ float blockSum256(float v) {
    __shared__ float red[4];
#pragma unroll
    for (int s = 32; s; s >>= 1) v += __shfl_down(v, s, 64);
    int l = threadIdx.x & 63, w = threadIdx.x >> 6;
    if (l == 0) red[w] = v;
    __syncthreads();
    return red[0] + red[1] + red[2] + red[3];
}

__device__ __forceinline__ void gload16(const void* g, void* lds) {
    __builtin_amdgcn_global_load_lds(
        (const __attribute__((address_space(1))) void*)g,
        (__attribute__((address_space(3))) void*)lds, 16, 0, 0);
}

// ---------------- convert fp32 -> bf16 + row sq-norms ----------------
__global__ __launch_bounds__(256) void k_convert_norm(const float* __restrict__ X, int sel) {
    u16* Xb = g_Feat + (size_t)sel * N_ * D_;
    float* nr = sel ? g_np : g_ng;
    int row = blockIdx.x;
    const float* xr = X + (size_t)row * D_;
    u16* xb = Xb + (size_t)row * D_;
    float s = 0.f;
    for (int c = threadIdx.x; c < D_; c += 256) {
        float v = xr[c];
        s += v * v;
        xb[c] = f2bf(v);
    }
    s = blockSum256(s);
    if (threadIdx.x == 0) nr[row] = s;
}

// ---------------- bf16 transpose [N_][D_] -> g_BT[D_][8192] ----------------
// sel=1 (Pb) -> cols 0..4095 ; sel=0 (Gb) -> cols 4096..8191
__global__ __launch_bounds__(256) void k_transpose(int sel) {
    const u16* in = g_Feat + (size_t)sel * N_ * D_;
    const int colofs = sel ? 0 : 4096;
    __shared__ u16 t[32][33];
    int c0 = blockIdx.x * 32, r0 = blockIdx.y * 32;
    int tx = threadIdx.x, ty = threadIdx.y;
#pragma unroll
    for (int k = 0; k < 32; k += 8)
        t[ty + k][tx] = in[(size_t)(r0 + ty + k) * D_ + c0 + tx];
    __syncthreads();
#pragma unroll
    for (int k = 0; k < 32; k += 8)
        g_BT[(size_t)(c0 + ty + k) * (2 * N_) + colofs + r0 + tx] = t[tx][ty + k];
}

// ---------------- 8-phase 256-row MFMA GEMM (T1+T2+T3+T4+T5) ----------------
// C[M, NF*64*nbx] = A[M,K] * B[rows,K]^T ; BM=256, BN=NF*64, BK=64.
// 512 threads = 8 waves (2 M x 4 N); per-wave output 128 x NF*16... (NF frags of 16).
// LDS ring: 8 half-slots x 16KB. Half-tiles split by K (A_k0,B_k0,A_k1,B_k1 per tile).
// Swizzle: LDS(row, cb) holds global (row, cb ^ ((row&3)<<4)); staged via pre-swizzled
// global source (linear LDS dest, rule 21), read with matching XOR.
// MODE 0: S GEMM  A=g_Gb部分 B=g_Feat(8192 rows) K=3072, split C -> Sn(j<4096)/Sp
// MODE 1: V GEMM  A=g_W B=g_BT K=8192, C=g_V ldc=3072, NF=3 (BN=192)
template <int MODE>
__global__ __launch_bounds__(512, 1) void k_gemm8() {
    constexpr int NF = (MODE == 1) ? 3 : 4;   // N frags per wave
    constexpr int BN = NF * 64;
    constexpr int K  = (MODE == 1) ? 2 * N_ : D_;
    constexpr int nbx = (MODE == 1) ? 16 : 32;
    constexpr int nt = K >> 6;
    constexpr int niter = nt >> 1;
    constexpr int ntm1 = nt - 1;

    const u16* A = (MODE == 1) ? g_W : g_Feat;
    const u16* B = (MODE == 1) ? g_BT : g_Feat;

    __shared__ u16 lds[65536];   // 128 KiB

    const int nwg = gridDim.x;
    const int cpx = nwg >> 3;
    const int bid = blockIdx.x;
    const int swz = (bid & 7) * cpx + (bid >> 3);
    const int by = swz / nbx, bx = swz - by * nbx;
    const int i0 = by * 256, j0 = bx * BN;

    const int tid = threadIdx.x;
    const int l = tid & 63, w = tid >> 6;
    const int wr = w >> 2, wc = w & 3;
    const int fr = l & 15, kg = l >> 4;

    // staging per-thread bases (pre-swizzled global source)
    const int slrow = w * 16 + (l >> 2);
    const int scol = ((l & 3) ^ ((l >> 2) & 3)) * 8;
    const u16* aB = A + (size_t)(i0 + slrow) * K + scol;
    const u16* bB = B + (size_t)(j0 + slrow) * K + scol;
    u16* ldsw = lds + w * 512;   // + slot*8192 (+4096 for q=1)

    f32x4 acc[8][NF] = {};

    // prologue: stage half-tiles H0..H5 (mat = h&1, khalf = (h>>1)&1, tile = h>>2)
#pragma unroll
    for (int h = 0; h < 6; ++h) {
        const int tau = h >> 2;
        const int kh = (h >> 1) & 1;
        const u16* g0 = ((h & 1) ? bB : aB) + tau * 64 + kh * 32;
        u16* lb = ldsw + h * 8192;
        gload16(g0, lb);
        gload16(g0 + (size_t)128 * K, lb + 4096);
    }

    for (int it = 0; it < niter; ++it) {
#pragma unroll
        for (int p = 0; p < 8; ++p) {
            if ((p & 1) == 0) asm volatile("s_waitcnt vmcnt(8)" ::: "memory");
            asm volatile("s_barrier" ::: "memory");

            // stage H[k+6]: slot (p+6)&7, tile 2it + 1+((p+2)>>2), khalf 1-((p>>1)&1)
            {
                int tau = 2 * it + 1 + ((p + 2) >> 2);
                if (tau > ntm1) tau = ntm1;                 // tail dummy (keeps vmcnt FIFO exact)
                const int slot = (p + 6) & 7;
                const int kh = 1 - ((p >> 1) & 1);
                const u16* g0 = ((p & 1) ? bB : aB) + tau * 64 + kh * 32;
                u16* lb = ldsw + slot * 8192;
                gload16(g0, lb);
                gload16(g0 + (size_t)128 * K, lb + 4096);
            }

            // ds reads: phase p reads tile (p>>2), kstep (p>>1)&1, m-half p&1
            const int sa = ((p >> 2) << 2) | (((p >> 1) & 1) << 1);
            const int sb = sa + 1;
            const int mb = (p & 1) << 2;
            bf16x8 av[4], bv[NF];
#pragma unroll
            for (int m = 0; m < 4; ++m) {
                int row = wr * 128 + (mb + m) * 16 + fr;
                av[m] = *(const bf16x8*)((const char*)lds + sa * 16384 + row * 64 + ((kg * 16) ^ ((row & 3) << 4)));
            }
#pragma unroll
            for (int n = 0; n < NF; ++n) {
                int row = wc * (NF * 16) + n * 16 + fr;
                bv[n] = *(const bf16x8*)((const char*)lds + sb * 16384 + row * 64 + ((kg * 16) ^ ((row & 3) << 4)));
            }
            __builtin_amdgcn_s_setprio(1);
#pragma unroll
            for (int m = 0; m < 4; ++m)
#pragma unroll
                for (int n = 0; n < NF; ++n)
                    acc[mb + m][n] = __builtin_amdgcn_mfma_f32_16x16x32_bf16(av[m], bv[n], acc[mb + m][n], 0, 0, 0);
            __builtin_amdgcn_s_setprio(0);
        }
    }

    // epilogue
    const int fq = l >> 4;
#pragma unroll
    for (int m = 0; m < 8; ++m)
#pragma unroll
        for (int n = 0; n < NF; ++n)
#pragma unroll
            for (int r = 0; r < 4; ++r) {
                int row = i0 + wr * 128 + m * 16 + fq * 4 + r;
                int col = j0 + wc * (NF * 16) + n * 16 + fr;
                float v = acc[m][n][r];
                if (MODE == 0) {
                    if (col < 4096) g_Sn[(size_t)row * 4096 + col] = v;
                    else            g_Sp[(size_t)row * 4096 + (col - 4096)] = v;
                } else {
                    g_V[(size_t)row * D_ + col] = v;
                }
            }
}

// ---------------- S -> dist (in place), diag mask for neg ----------------
__global__ __launch_bounds__(256) void k_s2dist(int sel) {
    float* Sd = sel ? g_Sn : g_Sp;
    const float* nb = sel ? g_ng : g_np;
    int i = blockIdx.y;
    int j = blockIdx.x * 256 + threadIdx.x;
    size_t idx = (size_t)i * N_ + j;
    float d2 = g_ng[i] + nb[j] - 2.f * Sd[idx];
    float d = sqrtf(fmaxf(d2, 0.f));
    if (sel && i == j) d += 1000000.0f;
    Sd[idx] = d;
}

// ---------------- row mins over both matrices ----------------
__global__ __launch_bounds__(256) void k_rowmin() {
    int i = blockIdx.x;
    const float* rp = g_Sp + (size_t)i * N_;
    const float* rn = g_Sn + (size_t)i * N_;
    float mp = 1e30f, mn = 1e30f;
    for (int j = threadIdx.x; j < N_; j += 256) {
        mp = fminf(mp, rp[j]);
        mn = fminf(mn, rn[j]);
    }
    __shared__ float red[2][4];
#pragma unroll
    for (int s = 32; s; s >>= 1) {
        mp = fminf(mp, __shfl_down(mp, s, 64));
        mn = fminf(mn, __shfl_down(mn, s, 64));
    }
    int l = threadIdx.x & 63, w = threadIdx.x >> 6;
    if (l == 0) { red[0][w] = mp; red[1][w] = mn; }
    __syncthreads();
    if (threadIdx.x == 0)
        g_rminp[i] = fminf(fminf(red[0][0], red[0][1]), fminf(red[0][2], red[0][3]));
    if (threadIdx.x == 1)
        g_rminn[i] = fminf(fminf(red[1][0], red[1][1]), fminf(red[1][2], red[1][3]));
}

// ---------------- column min of d_pos ----------------
__global__ __launch_bounds__(256) void k_colmin_init() {
    g_cminp[blockIdx.x * 256 + threadIdx.x] = 1e30f;
}
__global__ __launch_bounds__(256) void k_colmin() {
    int j = blockIdx.x * 256 + threadIdx.x;
    int i0 = blockIdx.y * 512;
    float m = 1e30f;
    for (int i = i0; i < i0 + 512; ++i)
        m = fminf(m, g_Sp[(size_t)i * N_ + j]);
    atomicMin((unsigned int*)&g_cminp[j], __float_as_uint(m));
}

// ---------------- row exp-sums ----------------
__global__ __launch_bounds__(256) void k_rowexp() {
    int i = blockIdx.x;
    float rd = fminf(g_rminp[i], g_rminn[i]);
    float rn = g_rminn[i];
    const float* rp = g_Sp + (size_t)i * N_;
    const float* rng = g_Sn + (size_t)i * N_;
    float v[6] = {0, 0, 0, 0, 0, 0};
    for (int j = threadIdx.x; j < N_; j += 256) {
        float e = rd - rp[j];
        v[0] += __expf(e * 50.f);
        v[1] += __expf(e * 20.f);
        v[2] += __expf(e * 5.f);
    }
    for (int j = threadIdx.x; j < N_; j += 256) {
        float d = rng[j];
        float e = rd - d, en = rn - d;
        v[0] += __expf(e * 50.f);
        v[1] += __expf(e * 20.f);
        v[2] += __expf(e * 5.f);
        v[3] += __expf(en * 50.f);
        v[4] += __expf(en * 20.f);
        v[5] += __expf(en * 5.f);
    }
    __shared__ float red[6][4];
#pragma unroll
    for (int k = 0; k < 6; ++k)
#pragma unroll
        for (int s = 32; s; s >>= 1) v[k] += __shfl_down(v[k], s, 64);
    int l = threadIdx.x & 63, w = threadIdx.x >> 6;
    if (l == 0)
#pragma unroll
        for (int k = 0; k < 6; ++k) red[k][w] = v[k];
    __syncthreads();
    int t = threadIdx.x;
    if (t < 6) {
        float s = red[t][0] + red[t][1] + red[t][2] + red[t][3];
        if (t < 3) g_R[t * N_ + i] = s;
        else g_Cn[(t - 3) * N_ + i] = s;
    }
}

// ---------------- column exp-sums of d_pos ----------------
__global__ __launch_bounds__(256) void k_colexp() {
    int j = blockIdx.x * 256 + threadIdx.x;
    int ch = blockIdx.y;
    int i0 = ch * 512;
    float cm = g_cminp[j];
    float a0 = 0, a1 = 0, a2 = 0;
    for (int i = i0; i < i0 + 512; ++i) {
        float e = cm - g_Sp[(size_t)i * N_ + j];
        a0 += __expf(e * 50.f);
        a1 += __expf(e * 20.f);
        a2 += __expf(e * 5.f);
    }
    g_Cpart[(size_t)ch * (3 * N_) + 0 * N_ + j] = a0;
    g_Cpart[(size_t)ch * (3 * N_) + 1 * N_ + j] = a1;
    g_Cpart[(size_t)ch * (3 * N_) + 2 * N_ + j] = a2;
}
__global__ __launch_bounds__(256) void k_colreduce() {
    int idx = blockIdx.x * 256 + threadIdx.x;
    float s = 0;
#pragma unroll
    for (int ch = 0; ch < 8; ++ch) s += g_Cpart[(size_t)ch * (3 * N_) + idx];
    g_Cp[idx] = s;
}

__global__ __launch_bounds__(256) void k_rsq_all() {
    int idx = blockIdx.x * 256 + threadIdx.x;
    g_R[idx] = rsqrtf(g_R[idx]);
    g_Cp[idx] = rsqrtf(g_Cp[idx]);
    g_Cn[idx] = rsqrtf(g_Cn[idx]);
}

// ---------------- row sums of A (pos and neg parts), all taus ----------------
__global__ __launch_bounds__(256) void k_rowsumA() {
    int i = blockIdx.x;
    float rd = fminf(g_rminp[i], g_rminn[i]);
    const float* rp = g_Sp + (size_t)i * N_;
    const float* rng = g_Sn + (size_t)i * N_;
    float v[6] = {0, 0, 0, 0, 0, 0};
    for (int j = threadIdx.x; j < N_; j += 256) {
        float base = 0.5f * (rd + g_cminp[j]) - rp[j];
        v[0] += __expf(base * 50.f) * g_Cp[0 * N_ + j];
        v[1] += __expf(base * 20.f) * g_Cp[1 * N_ + j];
        v[2] += __expf(base * 5.f) * g_Cp[2 * N_ + j];
    }
    for (int j = threadIdx.x; j < N_; j += 256) {
        float base = 0.5f * (rd + g_rminn[j]) - rng[j];
        v[3] += __expf(base * 50.f) * g_Cn[0 * N_ + j];
        v[4] += __expf(base * 20.f) * g_Cn[1 * N_ + j];
        v[5] += __expf(base * 5.f) * g_Cn[2 * N_ + j];
    }
    __shared__ float red[6][4];
#pragma unroll
    for (int k = 0; k < 6; ++k)
#pragma unroll
        for (int s = 32; s; s >>= 1) v[k] += __shfl_down(v[k], s, 64);
    int l = threadIdx.x & 63, w = threadIdx.x >> 6;
    if (l == 0)
#pragma unroll
        for (int k = 0; k < 6; ++k) red[k][w] = v[k];
    __syncthreads();
    int t = threadIdx.x;
    if (t < 6) {
        float s = red[t][0] + red[t][1] + red[t][2] + red[t][3];
        if (t < 3) g_spos[t * N_ + i] = s * g_R[t * N_ + i];
        else g_sneg[(t - 3) * N_ + i] = s * g_R[(t - 3) * N_ + i];
    }
}

// ---------------- W generation for one tau: [Wp | -Wn] ----------------
__global__ __launch_bounds__(256) void k_wgen(int t, float itau) {
    int i = blockIdx.y;
    int j = blockIdx.x * 256 + threadIdx.x;
    float rd = fminf(g_rminp[i], g_rminn[i]);
    float iRi = g_R[t * N_ + i];
    float spi = g_spos[t * N_ + i];
    float sni = g_sneg[t * N_ + i];
    size_t idx = (size_t)i * N_ + j;
    float d = g_Sp[idx];
    float Ap = __expf((0.5f * (rd + g_cminp[j]) - d) * itau) * iRi * g_Cp[t * N_ + j];
    g_W[(size_t)i * (2 * N_) + j] = f2bf(Ap * sni);
    d = g_Sn[idx];
    float An = __expf((0.5f * (rd + g_rminn[j]) - d) * itau) * iRi * g_Cn[t * N_ + j];
    g_W[(size_t)i * (2 * N_) + 4096 + j] = f2bf(-(An * spi));
}

// ---------------- sum of squares (V or Vt) ----------------
__global__ __launch_bounds__(256) void k_reduce_sq(int sel) {
    const float4* V = (const float4*)(sel ? g_Vt : g_V);
    const size_t n4 = (size_t)N_ * D_ / 4;
    float s = 0.f;
    for (size_t i = (size_t)blockIdx.x * 256 + threadIdx.x; i < n4; i += (size_t)1024 * 256) {
        float4 v = V[i];
        s += v.x * v.x + v.y * v.y + v.z * v.z + v.w * v.w;
    }
    s = blockSum256(s);
    if (threadIdx.x == 0) g_part[blockIdx.x] = s;
}

__global__ __launch_bounds__(256) void k_finalize(int mode, float* out) {
    int t = threadIdx.x;
    float s = g_part[t] + g_part[t + 256] + g_part[t + 512] + g_part[t + 768];
    s = blockSum256(s);
    if (t == 0) {
        float m = s / ((float)N_ * (float)D_);
        if (mode) out[0] = m / (m + 1e-8f);
        else g_scale[0] = rsqrtf(m + 1e-8f);
    }
}

__global__ __launch_bounds__(256) void k_vaccum(int first) {
    float sc = g_scale[0];
    float4* Vt = (float4*)g_Vt;
    const float4* V = (const float4*)g_V;
    const size_t n4 = (size_t)N_ * D_ / 4;
    for (size_t i = (size_t)blockIdx.x * 256 + threadIdx.x; i < n4; i += (size_t)2048 * 256) {
        float4 v = V[i];
        float4 o;
        if (first) { o.x = 0; o.y = 0; o.z = 0; o.w = 0; }
        else o = Vt[i];
        o.x += v.x * sc; o.y += v.y * sc; o.z += v.z * sc; o.w += v.w * sc;
        Vt[i] = o;
    }
}

// ---------------- host orchestration ----------------
extern "C" void kernel_launch(void* const* d_in, const int* in_sizes, int n_in,
                              void* d_out, int out_size, void* d_ws, size_t ws_size,
                              hipStream_t stream) {
    const float* xg = (const float*)d_in[0];
    const float* xp = (const float*)d_in[1];
    float* out = (float*)d_out;

    k_convert_norm<<<N_, 256, 0, stream>>>(xg, 0);
    k_convert_norm<<<N_, 256, 0, stream>>>(xp, 1);
    k_transpose<<<dim3(D_ / 32, N_ / 32), dim3(32, 8), 0, stream>>>(0);
    k_transpose<<<dim3(D_ / 32, N_ / 32), dim3(32, 8), 0, stream>>>(1);

    k_gemm8<0><<<512, 512, 0, stream>>>();   // Sn (cols<4096) | Sp

    k_s2dist<<<dim3(N_ / 256, N_), 256, 0, stream>>>(0);
    k_s2dist<<<dim3(N_ / 256, N_), 256, 0, stream>>>(1);

    k_rowmin<<<N_, 256, 0, stream>>>();
    k_colmin_init<<<N_ / 256, 256, 0, stream>>>();
    k_colmin<<<dim3(N_ / 256, 8), 256, 0, stream>>>();
    k_rowexp<<<N_, 256, 0, stream>>>();
    k_colexp<<<dim3(N_ / 256, 8), 256, 0, stream>>>();
    k_colreduce<<<3 * N_ / 256, 256, 0, stream>>>();
    k_rsq_all<<<3 * N_ / 256, 256, 0, stream>>>();
    k_rowsumA<<<N_, 256, 0, stream>>>();

    const float itau[3] = {50.f, 20.f, 5.f};
    for (int t = 0; t < 3; ++t) {
        k_wgen<<<dim3(N_ / 256, N_), 256, 0, stream>>>(t, itau[t]);
        k_gemm8<1><<<256, 512, 0, stream>>>();   // V = [Wp|-Wn] @ [P;G]
        k_reduce_sq<<<1024, 256, 0, stream>>>(0);
        k_finalize<<<1, 256, 0, stream>>>(0, out);
        k_vaccum<<<2048, 256, 0, stream>>>(t == 0 ? 1 : 0);
    }
    k_reduce_sq<<<1024, 256, 0, stream>>>(1);
    k_finalize<<<1, 256, 0, stream>>>(1, out);
}

// Round 4
// 1307.905 us; speedup vs baseline: 1.4035x; 1.0401x over previous
//
#include <hip/hip_runtime.h>
#include <hip/hip_bf16.h>

typedef unsigned short u16;
typedef short bf16x8 __attribute__((ext_vector_type(8)));
typedef float f32x4 __attribute__((ext_vector_type(4)));

#define N_ 4096
#define D_ 3072

// ---------------- static device workspace ----------------
__device__ __align__(256) u16  g_Feat[(size_t)2 * N_ * D_];      // [Gb ; Pb]
__device__ __align__(256) u16  g_BT[(size_t)(D_ + 64) * 2 * N_]; // [3072(+64)][8192] = [PbT | GbT]
__device__ __align__(256) u16  g_Wall[(size_t)3 * N_ * 2 * N_];  // [tau][4096][8192] = [Wp | -Wn]
__device__ __align__(256) float g_Sp[(size_t)N_ * N_];           // dist_pos
__device__ __align__(256) float g_Sn[(size_t)N_ * N_];           // dist_neg (+diag mask)
__device__ __align__(256) float g_V [(size_t)N_ * D_];
__device__ __align__(256) float g_Vt[(size_t)N_ * D_];
__device__ float g_ng[N_], g_np[N_];
__device__ float g_rminp[N_], g_rminn[N_], g_cminp[N_];
__device__ float g_R [3 * N_];   // row exp-sums -> rsqrt'd
__device__ float g_Cp[3 * N_];   // col exp-sums (pos) -> rsqrt'd
__device__ float g_Cn[3 * N_];   // col exp-sums (neg = row sums, symmetry) -> rsqrt'd
__device__ float g_Cpart[8 * 3 * N_];
__device__ float g_part[1024];
__device__ float g_scale[1];

// ---------------- helpers ----------------
__device__ __forceinline__ u16 f2bf(float f) {
    unsigned u = __float_as_uint(f);
    u += 0x7fffu + ((u >> 16) & 1u);
    return (u16)(u >> 16);
}

__device__ __forceinline__ float blockSum256(float v) {
    __shared__ float red[4];
#pragma unroll
    for (int s = 32; s; s >>= 1) v += __shfl_down(v, s, 64);
    int l = threadIdx.x & 63, w = threadIdx.x >> 6;
    if (l == 0) red[w] = v;
    __syncthreads();
    return red[0] + red[1] + red[2] + red[3];
}

__device__ __forceinline__ void gload16(const void* g, void* lds) {
    __builtin_amdgcn_global_load_lds(
        (const __attribute__((address_space(1))) void*)g,
        (__attribute__((address_space(3))) void*)lds, 16, 0, 0);
}

// ---------------- convert fp32 -> bf16 + row sq-norms ----------------
__global__ __launch_bounds__(256) void k_convert_norm(const float* __restrict__ X, int sel) {
    u16* Xb = g_Feat + (size_t)sel * N_ * D_;
    float* nr = sel ? g_np : g_ng;
    int row = blockIdx.x;
    const float* xr = X + (size_t)row * D_;
    u16* xb = Xb + (size_t)row * D_;
    float s = 0.f;
    for (int c = threadIdx.x; c < D_; c += 256) {
        float v = xr[c];
        s += v * v;
        xb[c] = f2bf(v);
    }
    s = blockSum256(s);
    if (threadIdx.x == 0) nr[row] = s;
}

// ---------------- bf16 transpose -> g_BT[D_][8192] ----------------
__global__ __launch_bounds__(256) void k_transpose(int sel) {
    const u16* in = g_Feat + (size_t)sel * N_ * D_;
    const int colofs = sel ? 0 : 4096;
    __shared__ u16 t[32][33];
    int c0 = blockIdx.x * 32, r0 = blockIdx.y * 32;
    int tx = threadIdx.x, ty = threadIdx.y;
#pragma unroll
    for (int k = 0; k < 32; k += 8)
        t[ty + k][tx] = in[(size_t)(r0 + ty + k) * D_ + c0 + tx];
    __syncthreads();
#pragma unroll
    for (int k = 0; k < 32; k += 8)
        g_BT[(size_t)(c0 + ty + k) * (2 * N_) + colofs + r0 + tx] = t[tx][ty + k];
}

// ---------------- 8-phase 256-row MFMA GEMM ----------------
// BM=256, BN=NF*64, BK=64; 8 waves (2Mx4N). LDS ring: 8 x 16KB half-slots
// (A_k0,B_k0,A_k1,B_k1 per 64-K tile). Phase: [even: vmcnt(8)] -> s_barrier ->
// stage slot(p+6) -> ds reads -> setprio/MFMA. Swizzle: LDS(row,chunk) holds
// global (row, chunk ^ ((row>>1)&3)); staged via pre-swizzled GLOBAL source
// (linear LDS dest, rule 21), read with matching XOR -> uniform 2-way (free).
// MODE 0 (tsel ignored): S = G.[G;P]^T, K=3072; epilogue -> dist -> g_Sn/g_Sp
// MODE 1 (tsel=tau): V = W_tau.[P;G], K=8192, NF=3; epilogue -> g_V + ssq partials
template <int MODE>
__global__ __launch_bounds__(512, 1) void k_gemm8(int tsel) {
    constexpr int NF = (MODE == 1) ? 3 : 4;
    constexpr int K  = (MODE == 1) ? 2 * N_ : D_;
    constexpr int nbx = (MODE == 1) ? 16 : 32;
    constexpr int nt = K >> 6;
    constexpr int niter = nt >> 1;
    constexpr int ntm1 = nt - 1;
    const u16* A = (MODE == 1) ? (g_Wall + (size_t)tsel * N_ * 2 * N_) : g_Feat;
    const u16* B = (MODE == 1) ? g_BT : g_Feat;

    __shared__ u16 lds[65536];   // 128 KiB

    const int nwg = gridDim.x;
    const int cpx = nwg >> 3;
    const int bid = blockIdx.x;
    const int swz = (bid & 7) * cpx + (bid >> 3);
    const int by = swz / nbx, bx = swz - by * nbx;
    const int i0 = by * 256, j0 = bx * (NF * 64);

    const int tid = threadIdx.x;
    const int l = tid & 63, w = tid >> 6;
    const int wr = w >> 2, wc = w & 3;
    const int fr = l & 15, kg = l >> 4;

    const int slrow = w * 16 + (l >> 2);
    const int scol = ((l & 3) ^ ((l >> 3) & 3)) * 8;    // inverse-swizzled source
    const u16* aB = A + (size_t)(i0 + slrow) * K + scol;
    const u16* bB = B + (size_t)(j0 + slrow) * K + scol;
    u16* ldsw = lds + w * 512;

    f32x4 acc[8][NF] = {};

    // prologue: half-tile blocks H0..H5 (mat=h&1, khalf=(h>>1)&1, tile=h>>2)
#pragma unroll
    for (int h = 0; h < 6; ++h) {
        const int tau = h >> 2;
        const int kh = (h >> 1) & 1;
        const u16* g0 = ((h & 1) ? bB : aB) + tau * 64 + kh * 32;
        u16* lb = ldsw + h * 8192;
        gload16(g0, lb);
        gload16(g0 + (size_t)128 * K, lb + 4096);
    }

    for (int it = 0; it < niter; ++it) {
#pragma unroll
        for (int p = 0; p < 8; ++p) {
            if ((p & 1) == 0) asm volatile("s_waitcnt vmcnt(8)" ::: "memory");
            asm volatile("s_barrier" ::: "memory");

            // stage block for phase +6 (exactly 2 gloads/phase keeps vmcnt FIFO exact)
            {
                int tau = 2 * it + 1 + ((p + 2) >> 2);
                if (tau > ntm1) tau = ntm1;                 // tail dummy
                const int slot = (p + 6) & 7;
                const int kh = 1 - ((p >> 1) & 1);
                const u16* g0 = ((p & 1) ? bB : aB) + tau * 64 + kh * 32;
                u16* lb = ldsw + slot * 8192;
                gload16(g0, lb);
                gload16(g0 + (size_t)128 * K, lb + 4096);
            }

            // ds reads: phase p reads tile (p>>2), kstep (p>>1)&1, m-half p&1
            const int sa = ((p >> 2) << 2) | (((p >> 1) & 1) << 1);
            const int sb = sa + 1;
            const int mb = (p & 1) << 2;
            bf16x8 av[4], bv[NF];
#pragma unroll
            for (int m = 0; m < 4; ++m) {
                int row = wr * 128 + (mb + m) * 16 + fr;
                av[m] = *(const bf16x8*)((const char*)lds + sa * 16384 + row * 64 + ((kg * 16) ^ (((row >> 1) & 3) << 4)));
            }
#pragma unroll
            for (int n = 0; n < NF; ++n) {
                int row = wc * (NF * 16) + n * 16 + fr;
                bv[n] = *(const bf16x8*)((const char*)lds + sb * 16384 + row * 64 + ((kg * 16) ^ (((row >> 1) & 3) << 4)));
            }
            __builtin_amdgcn_s_setprio(1);
#pragma unroll
            for (int m = 0; m < 4; ++m)
#pragma unroll
                for (int n = 0; n < NF; ++n)
                    acc[mb + m][n] = __builtin_amdgcn_mfma_f32_16x16x32_bf16(av[m], bv[n], acc[mb + m][n], 0, 0, 0);
            __builtin_amdgcn_s_setprio(0);
        }
    }

    const int fq = l >> 4;
    if (MODE == 0) {
        // epilogue: S -> dist (+diag mask), split Sn/Sp
#pragma unroll
        for (int m = 0; m < 8; ++m)
#pragma unroll
            for (int r = 0; r < 4; ++r) {
                int row = i0 + wr * 128 + m * 16 + fq * 4 + r;
                float ni = g_ng[row];
#pragma unroll
                for (int n = 0; n < NF; ++n) {
                    int col = j0 + wc * (NF * 16) + n * 16 + fr;
                    float v = acc[m][n][r];
                    if (col < 4096) {
                        float d2 = ni + g_ng[col] - 2.f * v;
                        float d = sqrtf(fmaxf(d2, 0.f));
                        if (col == row) d += 1000000.0f;
                        g_Sn[(size_t)row * 4096 + col] = d;
                    } else {
                        float d2 = ni + g_np[col - 4096] - 2.f * v;
                        g_Sp[(size_t)row * 4096 + (col - 4096)] = sqrtf(fmaxf(d2, 0.f));
                    }
                }
            }
    } else {
        float ssq = 0.f;
#pragma unroll
        for (int m = 0; m < 8; ++m)
#pragma unroll
            for (int n = 0; n < NF; ++n)
#pragma unroll
                for (int r = 0; r < 4; ++r) {
                    int row = i0 + wr * 128 + m * 16 + fq * 4 + r;
                    int col = j0 + wc * (NF * 16) + n * 16 + fr;
                    float v = acc[m][n][r];
                    g_V[(size_t)row * D_ + col] = v;
                    ssq += v * v;
                }
        // drain in-flight tail stages before reusing LDS (determinism)
        asm volatile("s_waitcnt vmcnt(0)" ::: "memory");
        __syncthreads();
#pragma unroll
        for (int s = 32; s; s >>= 1) ssq += __shfl_down(ssq, s, 64);
        float* redf = (float*)lds;
        if (l == 0) redf[w] = ssq;
        __syncthreads();
        if (tid == 0) {
            float s = 0;
#pragma unroll
            for (int k = 0; k < 8; ++k) s += redf[k];
            g_part[bid] = s;
        }
    }
}

// ---------------- per-row stats: mins + row exp-sums (LDS-staged) ----------------
__global__ __launch_bounds__(256) void k_rowstat() {
    __shared__ float sp[4096];
    __shared__ float sn[4096];
    __shared__ float red[6][4];
    __shared__ float bc[2];
    int i = blockIdx.x;
    const float4* rp4 = (const float4*)(g_Sp + (size_t)i * N_);
    const float4* rn4 = (const float4*)(g_Sn + (size_t)i * N_);
    float mp = 1e30f, mn = 1e30f;
    for (int c = threadIdx.x; c < 1024; c += 256) {
        float4 a = rp4[c], b = rn4[c];
        ((float4*)sp)[c] = a; ((float4*)sn)[c] = b;
        mp = fminf(mp, fminf(fminf(a.x, a.y), fminf(a.z, a.w)));
        mn = fminf(mn, fminf(fminf(b.x, b.y), fminf(b.z, b.w)));
    }
#pragma unroll
    for (int s = 32; s; s >>= 1) {
        mp = fminf(mp, __shfl_down(mp, s, 64));
        mn = fminf(mn, __shfl_down(mn, s, 64));
    }
    int l = threadIdx.x & 63, w = threadIdx.x >> 6;
    if (l == 0) { red[0][w] = mp; red[1][w] = mn; }
    __syncthreads();
    if (threadIdx.x == 0) {
        float a = fminf(fminf(red[0][0], red[0][1]), fminf(red[0][2], red[0][3]));
        float b = fminf(fminf(red[1][0], red[1][1]), fminf(red[1][2], red[1][3]));
        g_rminp[i] = a; g_rminn[i] = b;
        bc[0] = fminf(a, b); bc[1] = b;
    }
    __syncthreads();
    float rd = bc[0], rnn = bc[1];
    float v[6] = {0, 0, 0, 0, 0, 0};
    for (int j = threadIdx.x; j < 4096; j += 256) {
        float e = rd - sp[j];
        v[0] += __expf(e * 50.f);
        v[1] += __expf(e * 20.f);
        v[2] += __expf(e * 5.f);
        float d = sn[j];
        float e2 = rd - d, en = rnn - d;
        v[0] += __expf(e2 * 50.f);
        v[1] += __expf(e2 * 20.f);
        v[2] += __expf(e2 * 5.f);
        v[3] += __expf(en * 50.f);
        v[4] += __expf(en * 20.f);
        v[5] += __expf(en * 5.f);
    }
#pragma unroll
    for (int k = 0; k < 6; ++k)
#pragma unroll
        for (int s = 32; s; s >>= 1) v[k] += __shfl_down(v[k], s, 64);
    if (l == 0)
#pragma unroll
        for (int k = 0; k < 6; ++k) red[k][w] = v[k];
    __syncthreads();
    int t = threadIdx.x;
    if (t < 6) {
        float s = red[t][0] + red[t][1] + red[t][2] + red[t][3];
        if (t < 3) g_R[t * N_ + i] = s;
        else g_Cn[(t - 3) * N_ + i] = s;
    }
}

// ---------------- column min / exp-sums of d_pos ----------------
__global__ __launch_bounds__(256) void k_colmin_init() {
    g_cminp[blockIdx.x * 256 + threadIdx.x] = 1e30f;
}
__global__ __launch_bounds__(256) void k_colmin() {
    int j = blockIdx.x * 256 + threadIdx.x;
    int i0 = blockIdx.y * 512;
    float m = 1e30f;
    for (int i = i0; i < i0 + 512; ++i)
        m = fminf(m, g_Sp[(size_t)i * N_ + j]);
    atomicMin((unsigned int*)&g_cminp[j], __float_as_uint(m));
}
__global__ __launch_bounds__(256) void k_colexp() {
    int j = blockIdx.x * 256 + threadIdx.x;
    int ch = blockIdx.y;
    int i0 = ch * 512;
    float cm = g_cminp[j];
    float a0 = 0, a1 = 0, a2 = 0;
    for (int i = i0; i < i0 + 512; ++i) {
        float e = cm - g_Sp[(size_t)i * N_ + j];
        a0 += __expf(e * 50.f);
        a1 += __expf(e * 20.f);
        a2 += __expf(e * 5.f);
    }
    g_Cpart[(size_t)ch * (3 * N_) + 0 * N_ + j] = a0;
    g_Cpart[(size_t)ch * (3 * N_) + 1 * N_ + j] = a1;
    g_Cpart[(size_t)ch * (3 * N_) + 2 * N_ + j] = a2;
}
__global__ __launch_bounds__(256) void k_colreduce() {
    int idx = blockIdx.x * 256 + threadIdx.x;
    float s = 0;
#pragma unroll
    for (int ch = 0; ch < 8; ++ch) s += g_Cpart[(size_t)ch * (3 * N_) + idx];
    g_Cp[idx] = s;
}

__global__ __launch_bounds__(256) void k_rsq_all() {
    int idx = blockIdx.x * 256 + threadIdx.x;
    g_R[idx] = rsqrtf(g_R[idx]);
    g_Cp[idx] = rsqrtf(g_Cp[idx]);
    g_Cn[idx] = rsqrtf(g_Cn[idx]);
}

// ---------------- fused rowsumA + W generation (all 3 taus, one read) ----------
__global__ __launch_bounds__(256) void k_wfuse() {
    __shared__ float sp[4096];
    __shared__ float sn[4096];
    __shared__ float red[6][4];
    __shared__ float bc[6];
    int i = blockIdx.x;
    float rd = fminf(g_rminp[i], g_rminn[i]);
    const float4* rp4 = (const float4*)(g_Sp + (size_t)i * N_);
    const float4* rn4 = (const float4*)(g_Sn + (size_t)i * N_);
    for (int c = threadIdx.x; c < 1024; c += 256) {
        ((float4*)sp)[c] = rp4[c];
        ((float4*)sn)[c] = rn4[c];
    }
    __syncthreads();
    const float iR0 = g_R[i], iR1 = g_R[N_ + i], iR2 = g_R[2 * N_ + i];
    float v[6] = {0, 0, 0, 0, 0, 0};
    for (int j = threadIdx.x; j < 4096; j += 256) {
        float bp = 0.5f * (rd + g_cminp[j]) - sp[j];
        v[0] += __expf(bp * 50.f) * g_Cp[j];
        v[1] += __expf(bp * 20.f) * g_Cp[N_ + j];
        v[2] += __expf(bp * 5.f) * g_Cp[2 * N_ + j];
        float bn = 0.5f * (rd + g_rminn[j]) - sn[j];
        v[3] += __expf(bn * 50.f) * g_Cn[j];
        v[4] += __expf(bn * 20.f) * g_Cn[N_ + j];
        v[5] += __expf(bn * 5.f) * g_Cn[2 * N_ + j];
    }
    int l = threadIdx.x & 63, w = threadIdx.x >> 6;
#pragma unroll
    for (int k = 0; k < 6; ++k)
#pragma unroll
        for (int s = 32; s; s >>= 1) v[k] += __shfl_down(v[k], s, 64);
    if (l == 0)
#pragma unroll
        for (int k = 0; k < 6; ++k) red[k][w] = v[k];
    __syncthreads();
    if (threadIdx.x < 6) {
        int t = threadIdx.x;
        float s = red[t][0] + red[t][1] + red[t][2] + red[t][3];
        float iR = (t % 3 == 0) ? iR0 : ((t % 3 == 1) ? iR1 : iR2);
        bc[t] = s * iR;   // 0..2: spos_t ; 3..5: sneg_t
    }
    __syncthreads();
    const float sp0 = bc[0], sp1 = bc[1], sp2 = bc[2];
    const float sn0 = bc[3], sn1 = bc[4], sn2 = bc[5];
    for (int gq = threadIdx.x; gq < 512; gq += 256) {
        int j0 = gq * 8;
        u16 op[3][8], on[3][8];
#pragma unroll
        for (int e = 0; e < 8; ++e) {
            int j = j0 + e;
            float bp = 0.5f * (rd + g_cminp[j]) - sp[j];
            float bn = 0.5f * (rd + g_rminn[j]) - sn[j];
            op[0][e] = f2bf(__expf(bp * 50.f) * iR0 * g_Cp[j] * sn0);
            op[1][e] = f2bf(__expf(bp * 20.f) * iR1 * g_Cp[N_ + j] * sn1);
            op[2][e] = f2bf(__expf(bp * 5.f) * iR2 * g_Cp[2 * N_ + j] * sn2);
            on[0][e] = f2bf(-(__expf(bn * 50.f) * iR0 * g_Cn[j] * sp0));
            on[1][e] = f2bf(-(__expf(bn * 20.f) * iR1 * g_Cn[N_ + j] * sp1));
            on[2][e] = f2bf(-(__expf(bn * 5.f) * iR2 * g_Cn[2 * N_ + j] * sp2));
        }
#pragma unroll
        for (int t = 0; t < 3; ++t) {
            *(uint4*)&g_Wall[((size_t)t * N_ + i) * (2 * N_) + j0] = *(const uint4*)op[t];
            *(uint4*)&g_Wall[((size_t)t * N_ + i) * (2 * N_) + 4096 + j0] = *(const uint4*)on[t];
        }
    }
}

// ---------------- V_total accumulate (t=0 init, t=1 add) ----------------
__global__ __launch_bounds__(256) void k_vaccum(int first) {
    float sc = g_scale[0];
    float4* Vt = (float4*)g_Vt;
    const float4* V = (const float4*)g_V;
    const size_t n4 = (size_t)N_ * D_ / 4;
    for (size_t i = (size_t)blockIdx.x * 256 + threadIdx.x; i < n4; i += (size_t)2048 * 256) {
        float4 v = V[i];
        float4 o;
        if (first) { o.x = 0; o.y = 0; o.z = 0; o.w = 0; }
        else o = Vt[i];
        o.x += v.x * sc; o.y += v.y * sc; o.z += v.z * sc; o.w += v.w * sc;
        Vt[i] = o;
    }
}

// ---------------- final tau: (Vt + V*sc)^2 sum, no Vt write ----------------
__global__ __launch_bounds__(256) void k_vfinal() {
    float sc = g_scale[0];
    const float4* Vt = (const float4*)g_Vt;
    const float4* V = (const float4*)g_V;
    const size_t n4 = (size_t)N_ * D_ / 4;
    float s = 0.f;
    for (size_t i = (size_t)blockIdx.x * 256 + threadIdx.x; i < n4; i += (size_t)1024 * 256) {
        float4 v = V[i], o = Vt[i];
        float a = o.x + v.x * sc, b = o.y + v.y * sc, c = o.z + v.z * sc, d = o.w + v.w * sc;
        s += a * a + b * b + c * c + d * d;
    }
    s = blockSum256(s);
    if (threadIdx.x == 0) g_part[blockIdx.x] = s;
}

// mode 0: g_scale = rsqrt(mean+eps); mode 1: out[0] = m/(m+eps)
__global__ __launch_bounds__(256) void k_finalize(int nb, int mode, float* out) {
    float s = 0.f;
    for (int i = threadIdx.x; i < nb; i += 256) s += g_part[i];
    s = blockSum256(s);
    if (threadIdx.x == 0) {
        float m = s / ((float)N_ * (float)D_);
        if (mode) out[0] = m / (m + 1e-8f);
        else g_scale[0] = rsqrtf(m + 1e-8f);
    }
}

// ---------------- host orchestration ----------------
extern "C" void kernel_launch(void* const* d_in, const int* in_sizes, int n_in,
                              void* d_out, int out_size, void* d_ws, size_t ws_size,
                              hipStream_t stream) {
    const float* xg = (const float*)d_in[0];
    const float* xp = (const float*)d_in[1];
    float* out = (float*)d_out;

    k_convert_norm<<<N_, 256, 0, stream>>>(xg, 0);
    k_convert_norm<<<N_, 256, 0, stream>>>(xp, 1);
    k_transpose<<<dim3(D_ / 32, N_ / 32), dim3(32, 8), 0, stream>>>(0);
    k_transpose<<<dim3(D_ / 32, N_ / 32), dim3(32, 8), 0, stream>>>(1);

    k_gemm8<0><<<512, 512, 0, stream>>>(0);   // -> dist_neg | dist_pos

    k_rowstat<<<N_, 256, 0, stream>>>();
    k_colmin_init<<<N_ / 256, 256, 0, stream>>>();
    k_colmin<<<dim3(N_ / 256, 8), 256, 0, stream>>>();
    k_colexp<<<dim3(N_ / 256, 8), 256, 0, stream>>>();
    k_colreduce<<<3 * N_ / 256, 256, 0, stream>>>();
    k_rsq_all<<<3 * N_ / 256, 256, 0, stream>>>();
    k_wfuse<<<N_, 256, 0, stream>>>();

    for (int t = 0; t < 3; ++t) {
        k_gemm8<1><<<256, 512, 0, stream>>>(t);
        k_finalize<<<1, 256, 0, stream>>>(256, 0, out);
        if (t < 2) k_vaccum<<<2048, 256, 0, stream>>>(t == 0 ? 1 : 0);
        else       k_vfinal<<<1024, 256, 0, stream>>>();
    }
    k_finalize<<<1, 256, 0, stream>>>(1024, 1, out);
}

// Round 5
// 1275.942 us; speedup vs baseline: 1.4387x; 1.0251x over previous
//
#include <hip/hip_runtime.h>
#include <hip/hip_bf16.h>

typedef unsigned short u16;
typedef short bf16x8 __attribute__((ext_vector_type(8)));
typedef float f32x4 __attribute__((ext_vector_type(4)));

#define N_ 4096
#define D_ 3072

// ---------------- static device workspace ----------------
__device__ __align__(256) u16  g_Feat[(size_t)2 * N_ * D_];      // [Gb ; Pb]
__device__ __align__(256) u16  g_BT[(size_t)(D_ + 64) * 2 * N_]; // [3072(+64)][8192] = [PbT | GbT]
__device__ __align__(256) u16  g_Wall[(size_t)3 * N_ * 2 * N_];  // [tau][4096][8192] = [Wp | -Wn]
__device__ __align__(256) float g_Sp[(size_t)N_ * N_];           // dist_pos
__device__ __align__(256) float g_Sn[(size_t)N_ * N_];           // dist_neg (+diag mask)
__device__ __align__(256) float g_Vall[(size_t)3 * N_ * D_];     // V_tau, all taus
__device__ float g_ng[N_], g_np[N_];
__device__ float g_rminp[N_], g_rminn[N_], g_cminp[N_];
__device__ float g_R [3 * N_];    // rsqrt(row exp-sums)
__device__ float g_Cp[3 * N_];    // rsqrt(col exp-sums, pos)
__device__ float g_Cn[3 * N_];    // rsqrt(col exp-sums, neg = row sums by symmetry)
__device__ float g_cmp8[8 * N_];  // col-min partials
__device__ float g_Cpart[8 * 3 * N_];
__device__ float g_part3[3 * 256];  // per-tau ssq partials from V-GEMM
__device__ float g_part2[256];      // final ssq partials

// ---------------- helpers ----------------
__device__ __forceinline__ u16 f2bf(float f) {
    unsigned u = __float_as_uint(f);
    u += 0x7fffu + ((u >> 16) & 1u);
    return (u16)(u >> 16);
}

__device__ __forceinline__ float blockSum256(float v) {
    __shared__ float red[4];
#pragma unroll
    for (int s = 32; s; s >>= 1) v += __shfl_down(v, s, 64);
    int l = threadIdx.x & 63, w = threadIdx.x >> 6;
    if (l == 0) red[w] = v;
    __syncthreads();
    return red[0] + red[1] + red[2] + red[3];
}

__device__ __forceinline__ void gload16(const void* g, void* lds) {
    __builtin_amdgcn_global_load_lds(
        (const __attribute__((address_space(1))) void*)g,
        (__attribute__((address_space(3))) void*)lds, 16, 0, 0);
}

__device__ __forceinline__ unsigned ldsoff(const void* p) {
    return (unsigned)(size_t)(const __attribute__((address_space(3))) void*)p;
}

#define DSR128(dst, off) asm volatile("ds_read_b128 %0, %1" : "=v"(dst) : "v"(off))

// ---------------- convert fp32 -> bf16 + row sq-norms ----------------
__global__ __launch_bounds__(256) void k_convert_norm(const float* __restrict__ X, int sel) {
    u16* Xb = g_Feat + (size_t)sel * N_ * D_;
    float* nr = sel ? g_np : g_ng;
    int row = blockIdx.x;
    const float* xr = X + (size_t)row * D_;
    u16* xb = Xb + (size_t)row * D_;
    float s = 0.f;
    for (int c = threadIdx.x; c < D_; c += 256) {
        float v = xr[c];
        s += v * v;
        xb[c] = f2bf(v);
    }
    s = blockSum256(s);
    if (threadIdx.x == 0) nr[row] = s;
}

// ---------------- bf16 transpose -> g_BT[D_][8192] ----------------
__global__ __launch_bounds__(256) void k_transpose(int sel) {
    const u16* in = g_Feat + (size_t)sel * N_ * D_;
    const int colofs = sel ? 0 : 4096;
    __shared__ u16 t[32][33];
    int c0 = blockIdx.x * 32, r0 = blockIdx.y * 32;
    int tx = threadIdx.x, ty = threadIdx.y;
#pragma unroll
    for (int k = 0; k < 32; k += 8)
        t[ty + k][tx] = in[(size_t)(r0 + ty + k) * D_ + c0 + tx];
    __syncthreads();
#pragma unroll
    for (int k = 0; k < 32; k += 8)
        g_BT[(size_t)(c0 + ty + k) * (2 * N_) + colofs + r0 + tx] = t[tx][ty + k];
}

// ---------------- 8-phase 256-row MFMA GEMM ----------------
// BM=256, BN=NF*64, BK=64; 8 waves (2Mx4N). LDS ring: 8 x 16KB half-slots
// (A_k0,B_k0,A_k1,B_k1 per 64-K tile). Swizzle: LDS(row,chunk) holds global
// (row, chunk ^ ((row>>1)&3)); staged via pre-swizzled GLOBAL source (linear
// LDS dest), read with matching XOR -> uniform 2-way (free). Conflicts = 0 (R4).
// MODE 0: S = G.[G;P]^T, K=3072, NF=4; R4-proven schedule (vmcnt(8) every other
//   phase, in-phase compiler-tracked frag reads). Epilogue -> dist -> g_Sn/g_Sp.
// MODE 1: V_tau = W_tau.[P;G], K=8192, NF=3; read-ahead schedule: vmcnt(6)+
//   barrier every phase, asm ds_read of NEXT phase's frags, lgkmcnt(7)+
//   sched_barrier(0) (rule 18) before MFMA on current frags. Epilogue -> g_Vall
//   + per-tau ssq partials.
template <int MODE>
__global__ __launch_bounds__(512, 1) void k_gemm8(int tsel) {
    constexpr int NF = (MODE == 1) ? 3 : 4;
    constexpr int K  = (MODE == 1) ? 2 * N_ : D_;
    constexpr int nbx = (MODE == 1) ? 16 : 32;
    constexpr int nt = K >> 6;
    constexpr int niter = nt >> 1;
    constexpr int ntm1 = nt - 1;
    const u16* A = (MODE == 1) ? (g_Wall + (size_t)tsel * N_ * 2 * N_) : g_Feat;
    const u16* B = (MODE == 1) ? g_BT : g_Feat;

    __shared__ u16 lds[65536];   // 128 KiB

    const int nwg = gridDim.x;
    const int cpx = nwg >> 3;
    const int bid = blockIdx.x;
    const int swz = (bid & 7) * cpx + (bid >> 3);
    const int by = swz / nbx, bx = swz - by * nbx;
    const int i0 = by * 256, j0 = bx * (NF * 64);

    const int tid = threadIdx.x;
    const int l = tid & 63, w = tid >> 6;
    const int wr = w >> 2, wc = w & 3;
    const int fr = l & 15, kg = l >> 4;

    const int slrow = w * 16 + (l >> 2);
    const int scol = ((l & 3) ^ ((l >> 3) & 3)) * 8;    // inverse-swizzled source
    const u16* aB = A + (size_t)(i0 + slrow) * K + scol;
    const u16* bB = B + (size_t)(j0 + slrow) * K + scol;
    u16* ldsw = lds + w * 512;

    f32x4 acc[8][NF] = {};

    // prologue: half-tile blocks H0..H5 (mat=h&1, khalf=(h>>1)&1, tile=h>>2)
#pragma unroll
    for (int h = 0; h < 6; ++h) {
        const int tau = h >> 2;
        const int kh = (h >> 1) & 1;
        const u16* g0 = ((h & 1) ? bB : aB) + tau * 64 + kh * 32;
        u16* lb = ldsw + h * 8192;
        gload16(g0, lb);
        gload16(g0 + (size_t)128 * K, lb + 4096);
    }

    if constexpr (MODE == 0) {
        // ---------- R4-proven schedule, unchanged ----------
        for (int it = 0; it < niter; ++it) {
#pragma unroll
            for (int p = 0; p < 8; ++p) {
                if ((p & 1) == 0) asm volatile("s_waitcnt vmcnt(8)" ::: "memory");
                asm volatile("s_barrier" ::: "memory");
                {
                    int tau = 2 * it + 1 + ((p + 2) >> 2);
                    if (tau > ntm1) tau = ntm1;
                    const int slot = (p + 6) & 7;
                    const int kh = 1 - ((p >> 1) & 1);
                    const u16* g0 = ((p & 1) ? bB : aB) + tau * 64 + kh * 32;
                    u16* lb = ldsw + slot * 8192;
                    gload16(g0, lb);
                    gload16(g0 + (size_t)128 * K, lb + 4096);
                }
                const int sa = ((p >> 2) << 2) | (((p >> 1) & 1) << 1);
                const int sb = sa + 1;
                const int mb = (p & 1) << 2;
                bf16x8 av[4], bv[NF];
#pragma unroll
                for (int m = 0; m < 4; ++m) {
                    int row = wr * 128 + (mb + m) * 16 + fr;
                    av[m] = *(const bf16x8*)((const char*)lds + sa * 16384 + row * 64 + ((kg * 16) ^ (((row >> 1) & 3) << 4)));
                }
#pragma unroll
                for (int n = 0; n < NF; ++n) {
                    int row = wc * (NF * 16) + n * 16 + fr;
                    bv[n] = *(const bf16x8*)((const char*)lds + sb * 16384 + row * 64 + ((kg * 16) ^ (((row >> 1) & 3) << 4)));
                }
                __builtin_amdgcn_s_setprio(1);
#pragma unroll
                for (int m = 0; m < 4; ++m)
#pragma unroll
                    for (int n = 0; n < NF; ++n)
                        acc[mb + m][n] = __builtin_amdgcn_mfma_f32_16x16x32_bf16(av[m], bv[n], acc[mb + m][n], 0, 0, 0);
                __builtin_amdgcn_s_setprio(0);
            }
        }
    } else {
        // ---------- read-ahead schedule (frag double-buffer) ----------
        const unsigned ldsbase = ldsoff(lds);
        bf16x8 a0[4], a1[4], b0[NF], b1[NF];

#define READFRAGS(Q, AV, BV) {                                               \
        constexpr int q_ = (Q);                                              \
        constexpr int sa_ = ((q_ >> 2) << 2) | (((q_ >> 1) & 1) << 1);       \
        constexpr int mbn_ = (q_ & 1) << 2;                                  \
        _Pragma("unroll") for (int m = 0; m < 4; ++m) {                      \
            int row = wr * 128 + (mbn_ + m) * 16 + fr;                       \
            unsigned ad = ldsbase + sa_ * 16384u + row * 64 +                \
                          ((kg * 16) ^ (((row >> 1) & 3) << 4));             \
            DSR128(AV[m], ad); }                                             \
        _Pragma("unroll") for (int n = 0; n < NF; ++n) {                     \
            int row = wc * (NF * 16) + n * 16 + fr;                          \
            unsigned ad = ldsbase + (sa_ + 1) * 16384u + row * 64 +          \
                          ((kg * 16) ^ (((row >> 1) & 3) << 4));             \
            DSR128(BV[n], ad); } }

#define PH(P, AVC, BVC, AVN, BVN) {                                          \
        asm volatile("s_waitcnt vmcnt(6)" ::: "memory");                     \
        asm volatile("s_barrier" ::: "memory");                              \
        { int tau_ = 2 * it + 1 + (((P) + 2) >> 2);                          \
          if (tau_ > ntm1) tau_ = ntm1;                                      \
          const u16* g0 = (((P) & 1) ? bB : aB) + tau_ * 64 +                \
                          (1 - (((P) >> 1) & 1)) * 32;                       \
          u16* lb = ldsw + (((P) + 6) & 7) * 8192;                           \
          gload16(g0, lb); gload16(g0 + (size_t)128 * K, lb + 4096); }       \
        READFRAGS(((P) + 1) & 7, AVN, BVN);                                  \
        asm volatile("s_waitcnt lgkmcnt(7)" ::: "memory");                   \
        __builtin_amdgcn_sched_barrier(0);                                   \
        __builtin_amdgcn_s_setprio(1);                                       \
        { constexpr int mb_ = ((P) & 1) << 2;                                \
          _Pragma("unroll") for (int m = 0; m < 4; ++m)                      \
            _Pragma("unroll") for (int n = 0; n < NF; ++n)                   \
              acc[mb_ + m][n] = __builtin_amdgcn_mfma_f32_16x16x32_bf16(     \
                  AVC[m], BVC[n], acc[mb_ + m][n], 0, 0, 0); }               \
        __builtin_amdgcn_s_setprio(0);                                       \
    }

        // prologue reads for phase 0 (slots 0,1 landed after vmcnt(8): 12-8=4 oldest)
        asm volatile("s_waitcnt vmcnt(8)" ::: "memory");
        asm volatile("s_barrier" ::: "memory");
        READFRAGS(0, a0, b0);

        for (int it = 0; it < niter; ++it) {
            PH(0, a0, b0, a1, b1)
            PH(1, a1, b1, a0, b0)
            PH(2, a0, b0, a1, b1)
            PH(3, a1, b1, a0, b0)
            PH(4, a0, b0, a1, b1)
            PH(5, a1, b1, a0, b0)
            PH(6, a0, b0, a1, b1)
            PH(7, a1, b1, a0, b0)
        }
#undef PH
#undef READFRAGS
    }

    const int fq = l >> 4;
    if (MODE == 0) {
        // epilogue: S -> dist (+diag mask), split Sn/Sp
#pragma unroll
        for (int m = 0; m < 8; ++m)
#pragma unroll
            for (int r = 0; r < 4; ++r) {
                int row = i0 + wr * 128 + m * 16 + fq * 4 + r;
                float ni = g_ng[row];
#pragma unroll
                for (int n = 0; n < NF; ++n) {
                    int col = j0 + wc * (NF * 16) + n * 16 + fr;
                    float v = acc[m][n][r];
                    if (col < 4096) {
                        float d2 = ni + g_ng[col] - 2.f * v;
                        float d = sqrtf(fmaxf(d2, 0.f));
                        if (col == row) d += 1000000.0f;
                        g_Sn[(size_t)row * 4096 + col] = d;
                    } else {
                        float d2 = ni + g_np[col - 4096] - 2.f * v;
                        g_Sp[(size_t)row * 4096 + (col - 4096)] = sqrtf(fmaxf(d2, 0.f));
                    }
                }
            }
    } else {
        float* Vout = g_Vall + (size_t)tsel * N_ * D_;
        float ssq = 0.f;
#pragma unroll
        for (int m = 0; m < 8; ++m)
#pragma unroll
            for (int n = 0; n < NF; ++n)
#pragma unroll
                for (int r = 0; r < 4; ++r) {
                    int row = i0 + wr * 128 + m * 16 + fq * 4 + r;
                    int col = j0 + wc * (NF * 16) + n * 16 + fr;
                    float v = acc[m][n][r];
                    Vout[(size_t)row * D_ + col] = v;
                    ssq += v * v;
                }
        // drain in-flight tail stages + outstanding reads before reusing LDS
        asm volatile("s_waitcnt vmcnt(0)" ::: "memory");
        __syncthreads();
#pragma unroll
        for (int s = 32; s; s >>= 1) ssq += __shfl_down(ssq, s, 64);
        float* redf = (float*)lds;
        if (l == 0) redf[w] = ssq;
        __syncthreads();
        if (tid == 0) {
            float s = 0;
#pragma unroll
            for (int k = 0; k < 8; ++k) s += redf[k];
            g_part3[tsel * 256 + bid] = s;
        }
    }
}

// ---------------- per-row stats: mins + row exp-sums (LDS-staged) ----------------
__global__ __launch_bounds__(256) void k_rowstat() {
    __shared__ float sp[4096];
    __shared__ float sn[4096];
    __shared__ float red[6][4];
    __shared__ float bc[2];
    int i = blockIdx.x;
    const float4* rp4 = (const float4*)(g_Sp + (size_t)i * N_);
    const float4* rn4 = (const float4*)(g_Sn + (size_t)i * N_);
    float mp = 1e30f, mn = 1e30f;
    for (int c = threadIdx.x; c < 1024; c += 256) {
        float4 a = rp4[c], b = rn4[c];
        ((float4*)sp)[c] = a; ((float4*)sn)[c] = b;
        mp = fminf(mp, fminf(fminf(a.x, a.y), fminf(a.z, a.w)));
        mn = fminf(mn, fminf(fminf(b.x, b.y), fminf(b.z, b.w)));
    }
#pragma unroll
    for (int s = 32; s; s >>= 1) {
        mp = fminf(mp, __shfl_down(mp, s, 64));
        mn = fminf(mn, __shfl_down(mn, s, 64));
    }
    int l = threadIdx.x & 63, w = threadIdx.x >> 6;
    if (l == 0) { red[0][w] = mp; red[1][w] = mn; }
    __syncthreads();
    if (threadIdx.x == 0) {
        float a = fminf(fminf(red[0][0], red[0][1]), fminf(red[0][2], red[0][3]));
        float b = fminf(fminf(red[1][0], red[1][1]), fminf(red[1][2], red[1][3]));
        g_rminp[i] = a; g_rminn[i] = b;
        bc[0] = fminf(a, b); bc[1] = b;
    }
    __syncthreads();
    float rd = bc[0], rnn = bc[1];
    float v[6] = {0, 0, 0, 0, 0, 0};
    for (int j = threadIdx.x; j < 4096; j += 256) {
        float e = rd - sp[j];
        v[0] += __expf(e * 50.f);
        v[1] += __expf(e * 20.f);
        v[2] += __expf(e * 5.f);
        float d = sn[j];
        float e2 = rd - d, en = rnn - d;
        v[0] += __expf(e2 * 50.f);
        v[1] += __expf(e2 * 20.f);
        v[2] += __expf(e2 * 5.f);
        v[3] += __expf(en * 50.f);
        v[4] += __expf(en * 20.f);
        v[5] += __expf(en * 5.f);
    }
#pragma unroll
    for (int k = 0; k < 6; ++k)
#pragma unroll
        for (int s = 32; s; s >>= 1) v[k] += __shfl_down(v[k], s, 64);
    if (l == 0)
#pragma unroll
        for (int k = 0; k < 6; ++k) red[k][w] = v[k];
    __syncthreads();
    int t = threadIdx.x;
    if (t < 6) {
        float s = red[t][0] + red[t][1] + red[t][2] + red[t][3];
        if (t < 3) g_R[t * N_ + i] = rsqrtf(s);
        else g_Cn[(t - 3) * N_ + i] = rsqrtf(s);
    }
}

// ---------------- column min partials / exp-sums of d_pos ----------------
__global__ __launch_bounds__(256) void k_colminpart() {
    int j = blockIdx.x * 256 + threadIdx.x;
    int i0 = blockIdx.y * 512;
    float m = 1e30f;
    for (int i = i0; i < i0 + 512; ++i)
        m = fminf(m, g_Sp[(size_t)i * N_ + j]);
    g_cmp8[(size_t)blockIdx.y * N_ + j] = m;
}
__global__ __launch_bounds__(256) void k_colexp() {
    int j = blockIdx.x * 256 + threadIdx.x;
    int ch = blockIdx.y;
    int i0 = ch * 512;
    float cm = 1e30f;
#pragma unroll
    for (int c = 0; c < 8; ++c) cm = fminf(cm, g_cmp8[(size_t)c * N_ + j]);
    if (ch == 0) g_cminp[j] = cm;
    float a0 = 0, a1 = 0, a2 = 0;
    for (int i = i0; i < i0 + 512; ++i) {
        float e = cm - g_Sp[(size_t)i * N_ + j];
        a0 += __expf(e * 50.f);
        a1 += __expf(e * 20.f);
        a2 += __expf(e * 5.f);
    }
    g_Cpart[(size_t)ch * (3 * N_) + 0 * N_ + j] = a0;
    g_Cpart[(size_t)ch * (3 * N_) + 1 * N_ + j] = a1;
    g_Cpart[(size_t)ch * (3 * N_) + 2 * N_ + j] = a2;
}
__global__ __launch_bounds__(256) void k_colreduce() {
    int idx = blockIdx.x * 256 + threadIdx.x;
    float s = 0;
#pragma unroll
    for (int ch = 0; ch < 8; ++ch) s += g_Cpart[(size_t)ch * (3 * N_) + idx];
    g_Cp[idx] = rsqrtf(s);
}

// ---------------- fused rowsumA + W generation (all 3 taus, one read) ----------
__global__ __launch_bounds__(256) void k_wfuse() {
    __shared__ float sp[4096];
    __shared__ float sn[4096];
    __shared__ float red[6][4];
    __shared__ float bc[6];
    int i = blockIdx.x;
    float rd = fminf(g_rminp[i], g_rminn[i]);
    const float4* rp4 = (const float4*)(g_Sp + (size_t)i * N_);
    const float4* rn4 = (const float4*)(g_Sn + (size_t)i * N_);
    for (int c = threadIdx.x; c < 1024; c += 256) {
        ((float4*)sp)[c] = rp4[c];
        ((float4*)sn)[c] = rn4[c];
    }
    __syncthreads();
    const float iR0 = g_R[i], iR1 = g_R[N_ + i], iR2 = g_R[2 * N_ + i];
    float v[6] = {0, 0, 0, 0, 0, 0};
    for (int j = threadIdx.x; j < 4096; j += 256) {
        float bp = 0.5f * (rd + g_cminp[j]) - sp[j];
        v[0] += __expf(bp * 50.f) * g_Cp[j];
        v[1] += __expf(bp * 20.f) * g_Cp[N_ + j];
        v[2] += __expf(bp * 5.f) * g_Cp[2 * N_ + j];
        float bn = 0.5f * (rd + g_rminn[j]) - sn[j];
        v[3] += __expf(bn * 50.f) * g_Cn[j];
        v[4] += __expf(bn * 20.f) * g_Cn[N_ + j];
        v[5] += __expf(bn * 5.f) * g_Cn[2 * N_ + j];
    }
    int l = threadIdx.x & 63, w = threadIdx.x >> 6;
#pragma unroll
    for (int k = 0; k < 6; ++k)
#pragma unroll
        for (int s = 32; s; s >>= 1) v[k] += __shfl_down(v[k], s, 64);
    if (l == 0)
#pragma unroll
        for (int k = 0; k < 6; ++k) red[k][w] = v[k];
    __syncthreads();
    if (threadIdx.x < 6) {
        int t = threadIdx.x;
        float s = red[t][0] + red[t][1] + red[t][2] + red[t][3];
        float iR = (t % 3 == 0) ? iR0 : ((t % 3 == 1) ? iR1 : iR2);
        bc[t] = s * iR;   // 0..2: spos_t ; 3..5: sneg_t
    }
    __syncthreads();
    const float sp0 = bc[0], sp1 = bc[1], sp2 = bc[2];
    const float sn0 = bc[3], sn1 = bc[4], sn2 = bc[5];
    for (int gq = threadIdx.x; gq < 512; gq += 256) {
        int j0 = gq * 8;
        u16 op[3][8], on[3][8];
#pragma unroll
        for (int e = 0; e < 8; ++e) {
            int j = j0 + e;
            float bp = 0.5f * (rd + g_cminp[j]) - sp[j];
            float bn = 0.5f * (rd + g_rminn[j]) - sn[j];
            op[0][e] = f2bf(__expf(bp * 50.f) * iR0 * g_Cp[j] * sn0);
            op[1][e] = f2bf(__expf(bp * 20.f) * iR1 * g_Cp[N_ + j] * sn1);
            op[2][e] = f2bf(__expf(bp * 5.f) * iR2 * g_Cp[2 * N_ + j] * sn2);
            on[0][e] = f2bf(-(__expf(bn * 50.f) * iR0 * g_Cn[j] * sp0));
            on[1][e] = f2bf(-(__expf(bn * 20.f) * iR1 * g_Cn[N_ + j] * sp1));
            on[2][e] = f2bf(-(__expf(bn * 5.f) * iR2 * g_Cn[2 * N_ + j] * sp2));
        }
#pragma unroll
        for (int t = 0; t < 3; ++t) {
            *(uint4*)&g_Wall[((size_t)t * N_ + i) * (2 * N_) + j0] = *(const uint4*)op[t];
            *(uint4*)&g_Wall[((size_t)t * N_ + i) * (2 * N_) + 4096 + j0] = *(const uint4*)on[t];
        }
    }
}

// ---------------- combine: scales from partials, Vt = sum V_tau/rms, final ssq ----
__global__ __launch_bounds__(256) void k_vcombine() {
    __shared__ float scsh[3];
    __shared__ float redm[4];
    for (int tau = 0; tau < 3; ++tau) {
        float v = g_part3[tau * 256 + threadIdx.x];
#pragma unroll
        for (int s = 32; s; s >>= 1) v += __shfl_down(v, s, 64);
        int l = threadIdx.x & 63, w = threadIdx.x >> 6;
        if (l == 0) redm[w] = v;
        __syncthreads();
        if (threadIdx.x == 0)
            scsh[tau] = rsqrtf((redm[0] + redm[1] + redm[2] + redm[3]) /
                               ((float)N_ * (float)D_) + 1e-8f);
        __syncthreads();
    }
    const float s0 = scsh[0], s1 = scsh[1], s2 = scsh[2];
    const float4* V0 = (const float4*)g_Vall;
    const float4* V1 = (const float4*)(g_Vall + (size_t)N_ * D_);
    const float4* V2 = (const float4*)(g_Vall + (size_t)2 * N_ * D_);
    const size_t n4 = (size_t)N_ * D_ / 4;
    float ssq = 0.f;
    for (size_t i = (size_t)blockIdx.x * 256 + threadIdx.x; i < n4; i += (size_t)256 * 256) {
        float4 a = V0[i], b = V1[i], c = V2[i];
        float x = a.x * s0 + b.x * s1 + c.x * s2;
        float y = a.y * s0 + b.y * s1 + c.y * s2;
        float z = a.z * s0 + b.z * s1 + c.z * s2;
        float u = a.w * s0 + b.w * s1 + c.w * s2;
        ssq += x * x + y * y + z * z + u * u;
    }
    ssq = blockSum256(ssq);
    if (threadIdx.x == 0) g_part2[blockIdx.x] = ssq;
}

__global__ __launch_bounds__(256) void k_finalize(float* out) {
    float s = blockSum256(g_part2[threadIdx.x]);
    if (threadIdx.x == 0) {
        float m = s / ((float)N_ * (float)D_);
        out[0] = m / (m + 1e-8f);
    }
}

// ---------------- host orchestration ----------------
extern "C" void kernel_launch(void* const* d_in, const int* in_sizes, int n_in,
                              void* d_out, int out_size, void* d_ws, size_t ws_size,
                              hipStream_t stream) {
    const float* xg = (const float*)d_in[0];
    const float* xp = (const float*)d_in[1];
    float* out = (float*)d_out;

    k_convert_norm<<<N_, 256, 0, stream>>>(xg, 0);
    k_convert_norm<<<N_, 256, 0, stream>>>(xp, 1);
    k_transpose<<<dim3(D_ / 32, N_ / 32), dim3(32, 8), 0, stream>>>(0);
    k_transpose<<<dim3(D_ / 32, N_ / 32), dim3(32, 8), 0, stream>>>(1);

    k_gemm8<0><<<512, 512, 0, stream>>>(0);   // -> dist_neg | dist_pos

    k_rowstat<<<N_, 256, 0, stream>>>();
    k_colminpart<<<dim3(N_ / 256, 8), 256, 0, stream>>>();
    k_colexp<<<dim3(N_ / 256, 8), 256, 0, stream>>>();
    k_colreduce<<<3 * N_ / 256, 256, 0, stream>>>();
    k_wfuse<<<N_, 256, 0, stream>>>();

    for (int t = 0; t < 3; ++t)
        k_gemm8<1><<<256, 512, 0, stream>>>(t);   // -> g_Vall[t] + ssq partials

    k_vcombine<<<256, 256, 0, stream>>>();
    k_finalize<<<1, 256, 0, stream>>>(out);
}

// Round 6
// 1258.006 us; speedup vs baseline: 1.4592x; 1.0143x over previous
//
#include <hip/hip_runtime.h>
#include <hip/hip_bf16.h>

typedef unsigned short u16;
typedef short bf16x8 __attribute__((ext_vector_type(8)));
typedef float f32x4 __attribute__((ext_vector_type(4)));

#define N_ 4096
#define D_ 3072

// ---------------- static device workspace ----------------
__device__ __align__(256) u16  g_Feat[(size_t)2 * N_ * D_];      // [Gb ; Pb]
__device__ __align__(256) u16  g_BT[(size_t)(D_ + 64) * 2 * N_]; // [3072(+64)][8192] = [PbT | GbT]
__device__ __align__(256) u16  g_Wall[(size_t)3 * N_ * 2 * N_];  // [tau][4096][8192] = [Wp | -Wn]
__device__ __align__(256) float g_Sp[(size_t)N_ * N_];           // dist_pos
__device__ __align__(256) float g_Sn[(size_t)N_ * N_];           // dist_neg (+diag mask)
__device__ __align__(256) float g_Vall[(size_t)3 * N_ * D_];     // V_tau, all taus
__device__ float g_ng[N_], g_np[N_];
__device__ float g_rminp[N_], g_rminn[N_], g_cminp[N_];
__device__ float g_R [3 * N_];    // rsqrt(row exp-sums)
__device__ float g_Cp[3 * N_];    // rsqrt(col exp-sums, pos)
__device__ float g_Cn[3 * N_];    // rsqrt(col exp-sums, neg = row sums by symmetry)
__device__ float g_cmp8[8 * N_];  // col-min partials
__device__ float g_Cpart[8 * 3 * N_];
__device__ float g_part3[3 * 256];   // per-tau ssq partials from V-GEMM
__device__ float g_part2[1024];      // final ssq partials

// ---------------- helpers ----------------
__device__ __forceinline__ u16 f2bf(float f) {
    unsigned u = __float_as_uint(f);
    u += 0x7fffu + ((u >> 16) & 1u);
    return (u16)(u >> 16);
}

__device__ __forceinline__ float blockSum256(float v) {
    __shared__ float red[4];
#pragma unroll
    for (int s = 32; s; s >>= 1) v += __shfl_down(v, s, 64);
    int l = threadIdx.x & 63, w = threadIdx.x >> 6;
    if (l == 0) red[w] = v;
    __syncthreads();
    return red[0] + red[1] + red[2] + red[3];
}

__device__ __forceinline__ void gload16(const void* g, void* lds) {
    __builtin_amdgcn_global_load_lds(
        (const __attribute__((address_space(1))) void*)g,
        (__attribute__((address_space(3))) void*)lds, 16, 0, 0);
}

// ---------------- convert fp32 -> bf16 + row sq-norms ----------------
__global__ __launch_bounds__(256) void k_convert_norm(const float* __restrict__ X, int sel) {
    u16* Xb = g_Feat + (size_t)sel * N_ * D_;
    float* nr = sel ? g_np : g_ng;
    int row = blockIdx.x;
    const float* xr = X + (size_t)row * D_;
    u16* xb = Xb + (size_t)row * D_;
    float s = 0.f;
    for (int c = threadIdx.x; c < D_; c += 256) {
        float v = xr[c];
        s += v * v;
        xb[c] = f2bf(v);
    }
    s = blockSum256(s);
    if (threadIdx.x == 0) nr[row] = s;
}

// ---------------- bf16 transpose -> g_BT[D_][8192] ----------------
__global__ __launch_bounds__(256) void k_transpose(int sel) {
    const u16* in = g_Feat + (size_t)sel * N_ * D_;
    const int colofs = sel ? 0 : 4096;
    __shared__ u16 t[32][33];
    int c0 = blockIdx.x * 32, r0 = blockIdx.y * 32;
    int tx = threadIdx.x, ty = threadIdx.y;
#pragma unroll
    for (int k = 0; k < 32; k += 8)
        t[ty + k][tx] = in[(size_t)(r0 + ty + k) * D_ + c0 + tx];
    __syncthreads();
#pragma unroll
    for (int k = 0; k < 32; k += 8)
        g_BT[(size_t)(c0 + ty + k) * (2 * N_) + colofs + r0 + tx] = t[tx][ty + k];
}

// ---------------- 8-phase 256-row MFMA GEMM (m201-faithful skeleton) ----------
// BM=256, BN=NF*64, BK=64; 8 waves (2Mx4N). LDS ring: 8 x 16KB half-slots
// (A_k0,B_k0,A_k1,B_k1 per 64-K tile). Swizzle: LDS(row,chunk) holds global
// (row, chunk ^ ((row>>1)&3)); staged via pre-swizzled GLOBAL source (linear
// LDS dest, rule 21), read with matching XOR -> uniform 2-way (free, 0 conflicts R4).
// Segment p: vmcnt(6) -> READS(cluster p, pre-barrier: latency hides under
// barrier+others' MFMA) -> STAGE slot (p+6)&7 -> s_barrier -> lgkmcnt(0)+
// sched_barrier -> setprio/MFMA/setprio -> s_barrier (WAR protection).
// Ledger: vmcnt(6)@p confirms stages p-6..p-4; reads(p) use slots staged
// p-6/p-5, published by other waves' vmcnt(6)@(p-1) + post-MFMA barrier(p-1).
// Slot restaged at p+2 strictly after post-barrier(p+1) > last read. Airtight.
// MODE 0: S = G.[G;P]^T, K=3072, NF=4 -> dist epilogue -> g_Sn/g_Sp
// MODE 1: V_tau = W_tau.[P;G], K=8192, NF=3 -> g_Vall + ssq partials
template <int MODE>
__global__ __launch_bounds__(512, 1) void k_gemm8(int tsel) {
    constexpr int NF = (MODE == 1) ? 3 : 4;
    constexpr int K  = (MODE == 1) ? 2 * N_ : D_;
    constexpr int nbx = (MODE == 1) ? 16 : 32;
    constexpr int nt = K >> 6;
    constexpr int niter = nt >> 1;
    constexpr int ntm1 = nt - 1;
    const u16* A = (MODE == 1) ? (g_Wall + (size_t)tsel * N_ * 2 * N_) : g_Feat;
    const u16* B = (MODE == 1) ? g_BT : g_Feat;

    __shared__ u16 lds[65536];   // 128 KiB

    const int nwg = gridDim.x;
    const int cpx = nwg >> 3;
    const int bid = blockIdx.x;
    const int swz = (bid & 7) * cpx + (bid >> 3);
    const int by = swz / nbx, bx = swz - by * nbx;
    const int i0 = by * 256, j0 = bx * (NF * 64);

    const int tid = threadIdx.x;
    const int l = tid & 63, w = tid >> 6;
    const int wr = w >> 2, wc = w & 3;
    const int fr = l & 15, kg = l >> 4;

    const int slrow = w * 16 + (l >> 2);
    const int scol = ((l & 3) ^ ((l >> 3) & 3)) * 8;    // inverse-swizzled source
    const u16* aB = A + (size_t)(i0 + slrow) * K + scol;
    const u16* bB = B + (size_t)(j0 + slrow) * K + scol;
    u16* ldsw = lds + w * 512;

    f32x4 acc[8][NF] = {};

    // prologue: half-tile blocks H0..H5 (mat=h&1, khalf=(h>>1)&1, tile=h>>2)
#pragma unroll
    for (int h = 0; h < 6; ++h) {
        const int tau = h >> 2;
        const int kh = (h >> 1) & 1;
        const u16* g0 = ((h & 1) ? bB : aB) + tau * 64 + kh * 32;
        u16* lb = ldsw + h * 8192;
        gload16(g0, lb);
        gload16(g0 + (size_t)128 * K, lb + 4096);
    }
    // publish slots 0..2 for segments 0-1 reads (pre-loop confirmation barrier)
    asm volatile("s_waitcnt vmcnt(6)" ::: "memory");
    asm volatile("s_barrier" ::: "memory");

    for (int it = 0; it < niter; ++it) {
#pragma unroll
        for (int p = 0; p < 8; ++p) {
            asm volatile("s_waitcnt vmcnt(6)" ::: "memory");

            // READS for cluster p (pre-barrier; slots staged 6/5 segments ago)
            const int sa = ((p >> 2) << 2) | (((p >> 1) & 1) << 1);
            const int sb = sa + 1;
            const int mb = (p & 1) << 2;
            bf16x8 av[4], bv[NF];
#pragma unroll
            for (int m = 0; m < 4; ++m) {
                int row = wr * 128 + (mb + m) * 16 + fr;
                av[m] = *(const bf16x8*)((const char*)lds + sa * 16384 + row * 64 + ((kg * 16) ^ (((row >> 1) & 3) << 4)));
            }
#pragma unroll
            for (int n = 0; n < NF; ++n) {
                int row = wc * (NF * 16) + n * 16 + fr;
                bv[n] = *(const bf16x8*)((const char*)lds + sb * 16384 + row * 64 + ((kg * 16) ^ (((row >> 1) & 3) << 4)));
            }

            // STAGE slot (p+6)&7 (2 gloads/phase keeps vmcnt FIFO exact)
            {
                int tau = 2 * it + 1 + ((p + 2) >> 2);
                if (tau > ntm1) tau = ntm1;                 // tail dummy
                const int kh = 1 - ((p >> 1) & 1);
                const u16* g0 = ((p & 1) ? bB : aB) + tau * 64 + kh * 32;
                u16* lb = ldsw + ((p + 6) & 7) * 8192;
                gload16(g0, lb);
                gload16(g0 + (size_t)128 * K, lb + 4096);
            }

            asm volatile("s_barrier" ::: "memory");            // pre-MFMA
            asm volatile("s_waitcnt lgkmcnt(0)" ::: "memory");
            __builtin_amdgcn_sched_barrier(0);
            __builtin_amdgcn_s_setprio(1);
#pragma unroll
            for (int m = 0; m < 4; ++m)
#pragma unroll
                for (int n = 0; n < NF; ++n)
                    acc[mb + m][n] = __builtin_amdgcn_mfma_f32_16x16x32_bf16(av[m], bv[n], acc[mb + m][n], 0, 0, 0);
            __builtin_amdgcn_s_setprio(0);
            asm volatile("s_barrier" ::: "memory");            // post-MFMA (WAR)
        }
    }

    const int fq = l >> 4;
    if (MODE == 0) {
        // epilogue: S -> dist (+diag mask), split Sn/Sp
#pragma unroll
        for (int m = 0; m < 8; ++m)
#pragma unroll
            for (int r = 0; r < 4; ++r) {
                int row = i0 + wr * 128 + m * 16 + fq * 4 + r;
                float ni = g_ng[row];
#pragma unroll
                for (int n = 0; n < NF; ++n) {
                    int col = j0 + wc * (NF * 16) + n * 16 + fr;
                    float v = acc[m][n][r];
                    if (col < 4096) {
                        float d2 = ni + g_ng[col] - 2.f * v;
                        float d = sqrtf(fmaxf(d2, 0.f));
                        if (col == row) d += 1000000.0f;
                        g_Sn[(size_t)row * 4096 + col] = d;
                    } else {
                        float d2 = ni + g_np[col - 4096] - 2.f * v;
                        g_Sp[(size_t)row * 4096 + (col - 4096)] = sqrtf(fmaxf(d2, 0.f));
                    }
                }
            }
    } else {
        float* Vout = g_Vall + (size_t)tsel * N_ * D_;
        float ssq = 0.f;
#pragma unroll
        for (int m = 0; m < 8; ++m)
#pragma unroll
            for (int n = 0; n < NF; ++n)
#pragma unroll
                for (int r = 0; r < 4; ++r) {
                    int row = i0 + wr * 128 + m * 16 + fq * 4 + r;
                    int col = j0 + wc * (NF * 16) + n * 16 + fr;
                    float v = acc[m][n][r];
                    Vout[(size_t)row * D_ + col] = v;
                    ssq += v * v;
                }
        // drain in-flight tail stages before reusing LDS (determinism)
        asm volatile("s_waitcnt vmcnt(0)" ::: "memory");
        __syncthreads();
#pragma unroll
        for (int s = 32; s; s >>= 1) ssq += __shfl_down(ssq, s, 64);
        float* redf = (float*)lds;
        if (l == 0) redf[w] = ssq;
        __syncthreads();
        if (tid == 0) {
            float s = 0;
#pragma unroll
            for (int k = 0; k < 8; ++k) s += redf[k];
            g_part3[tsel * 256 + bid] = s;
        }
    }
}

// ---------------- per-row stats: mins + row exp-sums (LDS-staged) ----------------
__global__ __launch_bounds__(256) void k_rowstat() {
    __shared__ float sp[4096];
    __shared__ float sn[4096];
    __shared__ float red[6][4];
    __shared__ float bc[2];
    int i = blockIdx.x;
    const float4* rp4 = (const float4*)(g_Sp + (size_t)i * N_);
    const float4* rn4 = (const float4*)(g_Sn + (size_t)i * N_);
    float mp = 1e30f, mn = 1e30f;
    for (int c = threadIdx.x; c < 1024; c += 256) {
        float4 a = rp4[c], b = rn4[c];
        ((float4*)sp)[c] = a; ((float4*)sn)[c] = b;
        mp = fminf(mp, fminf(fminf(a.x, a.y), fminf(a.z, a.w)));
        mn = fminf(mn, fminf(fminf(b.x, b.y), fminf(b.z, b.w)));
    }
#pragma unroll
    for (int s = 32; s; s >>= 1) {
        mp = fminf(mp, __shfl_down(mp, s, 64));
        mn = fminf(mn, __shfl_down(mn, s, 64));
    }
    int l = threadIdx.x & 63, w = threadIdx.x >> 6;
    if (l == 0) { red[0][w] = mp; red[1][w] = mn; }
    __syncthreads();
    if (threadIdx.x == 0) {
        float a = fminf(fminf(red[0][0], red[0][1]), fminf(red[0][2], red[0][3]));
        float b = fminf(fminf(red[1][0], red[1][1]), fminf(red[1][2], red[1][3]));
        g_rminp[i] = a; g_rminn[i] = b;
        bc[0] = fminf(a, b); bc[1] = b;
    }
    __syncthreads();
    float rd = bc[0], rnn = bc[1];
    float v[6] = {0, 0, 0, 0, 0, 0};
    for (int j = threadIdx.x; j < 4096; j += 256) {
        float e = rd - sp[j];
        v[0] += __expf(e * 50.f);
        v[1] += __expf(e * 20.f);
        v[2] += __expf(e * 5.f);
        float d = sn[j];
        float e2 = rd - d, en = rnn - d;
        v[0] += __expf(e2 * 50.f);
        v[1] += __expf(e2 * 20.f);
        v[2] += __expf(e2 * 5.f);
        v[3] += __expf(en * 50.f);
        v[4] += __expf(en * 20.f);
        v[5] += __expf(en * 5.f);
    }
#pragma unroll
    for (int k = 0; k < 6; ++k)
#pragma unroll
        for (int s = 32; s; s >>= 1) v[k] += __shfl_down(v[k], s, 64);
    if (l == 0)
#pragma unroll
        for (int k = 0; k < 6; ++k) red[k][w] = v[k];
    __syncthreads();
    int t = threadIdx.x;
    if (t < 6) {
        float s = red[t][0] + red[t][1] + red[t][2] + red[t][3];
        if (t < 3) g_R[t * N_ + i] = rsqrtf(s);
        else g_Cn[(t - 3) * N_ + i] = rsqrtf(s);
    }
}

// ---------------- column min partials / exp-sums of d_pos ----------------
__global__ __launch_bounds__(256) void k_colminpart() {
    int j = blockIdx.x * 256 + threadIdx.x;
    int i0 = blockIdx.y * 512;
    float m = 1e30f;
    for (int i = i0; i < i0 + 512; ++i)
        m = fminf(m, g_Sp[(size_t)i * N_ + j]);
    g_cmp8[(size_t)blockIdx.y * N_ + j] = m;
}
__global__ __launch_bounds__(256) void k_colexp() {
    int j = blockIdx.x * 256 + threadIdx.x;
    int ch = blockIdx.y;
    int i0 = ch * 512;
    float cm = 1e30f;
#pragma unroll
    for (int c = 0; c < 8; ++c) cm = fminf(cm, g_cmp8[(size_t)c * N_ + j]);
    if (ch == 0) g_cminp[j] = cm;
    float a0 = 0, a1 = 0, a2 = 0;
    for (int i = i0; i < i0 + 512; ++i) {
        float e = cm - g_Sp[(size_t)i * N_ + j];
        a0 += __expf(e * 50.f);
        a1 += __expf(e * 20.f);
        a2 += __expf(e * 5.f);
    }
    g_Cpart[(size_t)ch * (3 * N_) + 0 * N_ + j] = a0;
    g_Cpart[(size_t)ch * (3 * N_) + 1 * N_ + j] = a1;
    g_Cpart[(size_t)ch * (3 * N_) + 2 * N_ + j] = a2;
}
__global__ __launch_bounds__(256) void k_colreduce() {
    int idx = blockIdx.x * 256 + threadIdx.x;
    float s = 0;
#pragma unroll
    for (int ch = 0; ch < 8; ++ch) s += g_Cpart[(size_t)ch * (3 * N_) + idx];
    g_Cp[idx] = rsqrtf(s);
}

// ---------------- fused rowsumA + W generation (all 3 taus, one read) ----------
__global__ __launch_bounds__(256) void k_wfuse() {
    __shared__ float sp[4096];
    __shared__ float sn[4096];
    __shared__ float red[6][4];
    __shared__ float bc[6];
    int i = blockIdx.x;
    float rd = fminf(g_rminp[i], g_rminn[i]);
    const float4* rp4 = (const float4*)(g_Sp + (size_t)i * N_);
    const float4* rn4 = (const float4*)(g_Sn + (size_t)i * N_);
    for (int c = threadIdx.x; c < 1024; c += 256) {
        ((float4*)sp)[c] = rp4[c];
        ((float4*)sn)[c] = rn4[c];
    }
    __syncthreads();
    const float iR0 = g_R[i], iR1 = g_R[N_ + i], iR2 = g_R[2 * N_ + i];
    float v[6] = {0, 0, 0, 0, 0, 0};
    for (int j = threadIdx.x; j < 4096; j += 256) {
        float bp = 0.5f * (rd + g_cminp[j]) - sp[j];
        v[0] += __expf(bp * 50.f) * g_Cp[j];
        v[1] += __expf(bp * 20.f) * g_Cp[N_ + j];
        v[2] += __expf(bp * 5.f) * g_Cp[2 * N_ + j];
        float bn = 0.5f * (rd + g_rminn[j]) - sn[j];
        v[3] += __expf(bn * 50.f) * g_Cn[j];
        v[4] += __expf(bn * 20.f) * g_Cn[N_ + j];
        v[5] += __expf(bn * 5.f) * g_Cn[2 * N_ + j];
    }
    int l = threadIdx.x & 63, w = threadIdx.x >> 6;
#pragma unroll
    for (int k = 0; k < 6; ++k)
#pragma unroll
        for (int s = 32; s; s >>= 1) v[k] += __shfl_down(v[k], s, 64);
    if (l == 0)
#pragma unroll
        for (int k = 0; k < 6; ++k) red[k][w] = v[k];
    __syncthreads();
    if (threadIdx.x < 6) {
        int t = threadIdx.x;
        float s = red[t][0] + red[t][1] + red[t][2] + red[t][3];
        float iR = (t % 3 == 0) ? iR0 : ((t % 3 == 1) ? iR1 : iR2);
        bc[t] = s * iR;   // 0..2: spos_t ; 3..5: sneg_t
    }
    __syncthreads();
    const float sp0 = bc[0], sp1 = bc[1], sp2 = bc[2];
    const float sn0 = bc[3], sn1 = bc[4], sn2 = bc[5];
    for (int gq = threadIdx.x; gq < 512; gq += 256) {
        int j0 = gq * 8;
        u16 op[3][8], on[3][8];
#pragma unroll
        for (int e = 0; e < 8; ++e) {
            int j = j0 + e;
            float bp = 0.5f * (rd + g_cminp[j]) - sp[j];
            float bn = 0.5f * (rd + g_rminn[j]) - sn[j];
            op[0][e] = f2bf(__expf(bp * 50.f) * iR0 * g_Cp[j] * sn0);
            op[1][e] = f2bf(__expf(bp * 20.f) * iR1 * g_Cp[N_ + j] * sn1);
            op[2][e] = f2bf(__expf(bp * 5.f) * iR2 * g_Cp[2 * N_ + j] * sn2);
            on[0][e] = f2bf(-(__expf(bn * 50.f) * iR0 * g_Cn[j] * sp0));
            on[1][e] = f2bf(-(__expf(bn * 20.f) * iR1 * g_Cn[N_ + j] * sp1));
            on[2][e] = f2bf(-(__expf(bn * 5.f) * iR2 * g_Cn[2 * N_ + j] * sp2));
        }
#pragma unroll
        for (int t = 0; t < 3; ++t) {
            *(uint4*)&g_Wall[((size_t)t * N_ + i) * (2 * N_) + j0] = *(const uint4*)op[t];
            *(uint4*)&g_Wall[((size_t)t * N_ + i) * (2 * N_) + 4096 + j0] = *(const uint4*)on[t];
        }
    }
}

// ---------------- combine: scales from partials, Vt = sum V_tau/rms, final ssq ----
__global__ __launch_bounds__(256) void k_vcombine() {
    __shared__ float scsh[3];
    __shared__ float redm[4];
    for (int tau = 0; tau < 3; ++tau) {
        float v = g_part3[tau * 256 + threadIdx.x];
#pragma unroll
        for (int s = 32; s; s >>= 1) v += __shfl_down(v, s, 64);
        int l = threadIdx.x & 63, w = threadIdx.x >> 6;
        if (l == 0) redm[w] = v;
        __syncthreads();
        if (threadIdx.x == 0)
            scsh[tau] = rsqrtf((redm[0] + redm[1] + redm[2] + redm[3]) /
                               ((float)N_ * (float)D_) + 1e-8f);
        __syncthreads();
    }
    const float s0 = scsh[0], s1 = scsh[1], s2 = scsh[2];
    const float4* V0 = (const float4*)g_Vall;
    const float4* V1 = (const float4*)(g_Vall + (size_t)N_ * D_);
    const float4* V2 = (const float4*)(g_Vall + (size_t)2 * N_ * D_);
    const size_t n4 = (size_t)N_ * D_ / 4;
    float ssq = 0.f;
    for (size_t i = (size_t)blockIdx.x * 256 + threadIdx.x; i < n4; i += (size_t)1024 * 256) {
        float4 a = V0[i], b = V1[i], c = V2[i];
        float x = a.x * s0 + b.x * s1 + c.x * s2;
        float y = a.y * s0 + b.y * s1 + c.y * s2;
        float z = a.z * s0 + b.z * s1 + c.z * s2;
        float u = a.w * s0 + b.w * s1 + c.w * s2;
        ssq += x * x + y * y + z * z + u * u;
    }
    ssq = blockSum256(ssq);
    if (threadIdx.x == 0) g_part2[blockIdx.x] = ssq;
}

__global__ __launch_bounds__(256) void k_finalize(float* out) {
    float s = 0.f;
    for (int i = threadIdx.x; i < 1024; i += 256) s += g_part2[i];
    s = blockSum256(s);
    if (threadIdx.x == 0) {
        float m = s / ((float)N_ * (float)D_);
        out[0] = m / (m + 1e-8f);
    }
}

// ---------------- host orchestration ----------------
extern "C" void kernel_launch(void* const* d_in, const int* in_sizes, int n_in,
                              void* d_out, int out_size, void* d_ws, size_t ws_size,
                              hipStream_t stream) {
    const float* xg = (const float*)d_in[0];
    const float* xp = (const float*)d_in[1];
    float* out = (float*)d_out;

    k_convert_norm<<<N_, 256, 0, stream>>>(xg, 0);
    k_convert_norm<<<N_, 256, 0, stream>>>(xp, 1);
    k_transpose<<<dim3(D_ / 32, N_ / 32), dim3(32, 8), 0, stream>>>(0);
    k_transpose<<<dim3(D_ / 32, N_ / 32), dim3(32, 8), 0, stream>>>(1);

    k_gemm8<0><<<512, 512, 0, stream>>>(0);   // -> dist_neg | dist_pos

    k_rowstat<<<N_, 256, 0, stream>>>();
    k_colminpart<<<dim3(N_ / 256, 8), 256, 0, stream>>>();
    k_colexp<<<dim3(N_ / 256, 8), 256, 0, stream>>>();
    k_colreduce<<<3 * N_ / 256, 256, 0, stream>>>();
    k_wfuse<<<N_, 256, 0, stream>>>();

    for (int t = 0; t < 3; ++t)
        k_gemm8<1><<<256, 512, 0, stream>>>(t);   // -> g_Vall[t] + ssq partials

    k_vcombine<<<1024, 256, 0, stream>>>();
    k_finalize<<<1, 256, 0, stream>>>(out);
}

// Round 7
// 1126.440 us; speedup vs baseline: 1.6296x; 1.1168x over previous
//
#include <hip/hip_runtime.h>
#include <hip/hip_bf16.h>

typedef unsigned short u16;
typedef short bf16x8 __attribute__((ext_vector_type(8)));
typedef float f32x4 __attribute__((ext_vector_type(4)));

#define N_ 4096
#define D_ 3072

// ---------------- static device workspace ----------------
__device__ __align__(256) u16  g_Feat[(size_t)2 * N_ * D_];      // [Gb ; Pb]
__device__ __align__(256) u16  g_BT[(size_t)(D_ + 64) * 2 * N_]; // [3072(+64)][8192] = [PbT | GbT]
__device__ __align__(256) u16  g_Wall[(size_t)3 * N_ * 2 * N_];  // [tau][4096][8192] = [Wp | -Wn]
__device__ __align__(256) float g_Sp[(size_t)N_ * N_];           // dist_pos
__device__ __align__(256) float g_Sn[(size_t)N_ * N_];           // dist_neg (+diag mask)
__device__ __align__(256) float g_Vall[(size_t)3 * N_ * D_];     // V_tau, all taus
__device__ float g_ng[N_], g_np[N_];
__device__ float g_rminp[N_], g_rminn[N_], g_cminp[N_];          // via atomicMin in S-GEMM
__device__ float g_R [3 * N_];    // rsqrt(row exp-sums)
__device__ float g_Cp[3 * N_];    // rsqrt(col exp-sums, pos)
__device__ float g_Cn[3 * N_];    // rsqrt(col exp-sums, neg = row sums by symmetry)
__device__ float g_Cpart[8 * 3 * N_];
__device__ float g_part3[3 * 256];   // per-tau ssq partials from V-GEMM
__device__ float g_part2[1024];      // final ssq partials

// ---------------- helpers ----------------
__device__ __forceinline__ u16 f2bf(float f) {
    unsigned u = __float_as_uint(f);
    u += 0x7fffu + ((u >> 16) & 1u);
    return (u16)(u >> 16);
}

__device__ __forceinline__ float blockSum256(float v) {
    __shared__ float red[4];
#pragma unroll
    for (int s = 32; s; s >>= 1) v += __shfl_down(v, s, 64);
    int l = threadIdx.x & 63, w = threadIdx.x >> 6;
    if (l == 0) red[w] = v;
    __syncthreads();
    return red[0] + red[1] + red[2] + red[3];
}

__device__ __forceinline__ void gload16(const void* g, void* lds) {
    __builtin_amdgcn_global_load_lds(
        (const __attribute__((address_space(1))) void*)g,
        (__attribute__((address_space(3))) void*)lds, 16, 0, 0);
}

__device__ __forceinline__ void atomicMinF(float* p, float v) {
    atomicMin((unsigned int*)p, __float_as_uint(v));   // exact for v >= 0
}

// ---------------- convert fp32 -> bf16 + row sq-norms ----------------
__global__ __launch_bounds__(256) void k_convert_norm(const float* __restrict__ X, int sel) {
    u16* Xb = g_Feat + (size_t)sel * N_ * D_;
    float* nr = sel ? g_np : g_ng;
    int row = blockIdx.x;
    const float* xr = X + (size_t)row * D_;
    u16* xb = Xb + (size_t)row * D_;
    float s = 0.f;
    for (int c = threadIdx.x; c < D_; c += 256) {
        float v = xr[c];
        s += v * v;
        xb[c] = f2bf(v);
    }
    s = blockSum256(s);
    if (threadIdx.x == 0) nr[row] = s;
}

// ---------------- bf16 transpose -> g_BT[D_][8192] ----------------
__global__ __launch_bounds__(256) void k_transpose(int sel) {
    const u16* in = g_Feat + (size_t)sel * N_ * D_;
    const int colofs = sel ? 0 : 4096;
    __shared__ u16 t[32][33];
    int c0 = blockIdx.x * 32, r0 = blockIdx.y * 32;
    int tx = threadIdx.x, ty = threadIdx.y;
#pragma unroll
    for (int k = 0; k < 32; k += 8)
        t[ty + k][tx] = in[(size_t)(r0 + ty + k) * D_ + c0 + tx];
    __syncthreads();
#pragma unroll
    for (int k = 0; k < 32; k += 8)
        g_BT[(size_t)(c0 + ty + k) * (2 * N_) + colofs + r0 + tx] = t[tx][ty + k];
}

// ---------------- init min arrays ----------------
__global__ __launch_bounds__(256) void k_mininit() {
    int idx = blockIdx.x * 256 + threadIdx.x;   // 0..3*N_-1
    if (idx < N_) g_rminp[idx] = 1e30f;
    else if (idx < 2 * N_) g_rminn[idx - N_] = 1e30f;
    else g_cminp[idx - 2 * N_] = 1e30f;
}

// ---------------- 8-phase 256-row MFMA GEMM ----------------
// BM=256, BN=NF*64, BK=64; 8 waves (2Mx4N). LDS ring: 8 x 16KB half-slots
// (A_k0,B_k0,A_k1,B_k1 per 64-K tile). Swizzle: LDS(row,chunk) holds global
// (row, chunk ^ ((row>>1)&3)); pre-swizzled GLOBAL source (linear LDS dest),
// matching XOR on read -> uniform 2-way (free; conflicts=0 verified R4).
// Schedule (R6-verified): vmcnt(6) -> reads -> stage slot(p+6) -> barrier ->
// lgkmcnt(0)+sched_barrier -> setprio/MFMA -> barrier.
// MODE 0: S = G.G^T (triangle, mirrored) and G.P^T; K=3072, NF=4.
//   Grid 392 = 256 Sp blocks + 136 Sn upper-tri blocks. Epilogue: dist (+diag
//   mask), mirror store for off-diag Sn, atomicMin row/col mins.
// MODE 1: V_tau = W_tau.[P;G], K=8192, NF=3 -> g_Vall + ssq partials.
template <int MODE>
__global__ __launch_bounds__(512, 1) void k_gemm8(int tsel) {
    constexpr int NF = (MODE == 1) ? 3 : 4;
    constexpr int K  = (MODE == 1) ? 2 * N_ : D_;
    constexpr int nt = K >> 6;
    constexpr int niter = nt >> 1;
    constexpr int ntm1 = nt - 1;
    const u16* A = (MODE == 1) ? (g_Wall + (size_t)tsel * N_ * 2 * N_) : g_Feat;
    const u16* B = (MODE == 1) ? g_BT : g_Feat;

    __shared__ u16 lds[65536];   // 128 KiB

    const int nwg = gridDim.x;
    const int cpx = nwg >> 3;
    const int bid = blockIdx.x;
    const int swz = (bid & 7) * cpx + (bid >> 3);

    int i0, j0, jfeat;           // jfeat = row base within B matrix
    bool isSn = false, isDiag = false;
    if (MODE == 1) {
        const int by = swz >> 4, bx = swz & 15;
        i0 = by * 256; j0 = bx * (NF * 64); jfeat = j0;
    } else {
        if (swz < 256) {                       // Sp block
            const int by = swz >> 4, bx = swz & 15;
            i0 = by * 256; j0 = bx * 256; jfeat = 4096 + j0;
        } else {                               // Sn upper-triangle block
            int t = swz - 256, by = 0;
            while (t >= 16 - by) { t -= 16 - by; ++by; }
            const int bx = by + t;
            i0 = by * 256; j0 = bx * 256; jfeat = j0;
            isSn = true; isDiag = (bx == by);
        }
    }

    const int tid = threadIdx.x;
    const int l = tid & 63, w = tid >> 6;
    const int wr = w >> 2, wc = w & 3;
    const int fr = l & 15, kg = l >> 4;

    const int slrow = w * 16 + (l >> 2);
    const int scol = ((l & 3) ^ ((l >> 3) & 3)) * 8;    // inverse-swizzled source
    const u16* aB = A + (size_t)(i0 + slrow) * K + scol;
    const u16* bB = B + (size_t)(jfeat + slrow) * K + scol;
    u16* ldsw = lds + w * 512;

    f32x4 acc[8][NF] = {};

    // prologue: half-tile blocks H0..H5 (mat=h&1, khalf=(h>>1)&1, tile=h>>2)
#pragma unroll
    for (int h = 0; h < 6; ++h) {
        const int tau = h >> 2;
        const int kh = (h >> 1) & 1;
        const u16* g0 = ((h & 1) ? bB : aB) + tau * 64 + kh * 32;
        u16* lb = ldsw + h * 8192;
        gload16(g0, lb);
        gload16(g0 + (size_t)128 * K, lb + 4096);
    }
    asm volatile("s_waitcnt vmcnt(6)" ::: "memory");
    asm volatile("s_barrier" ::: "memory");

    for (int it = 0; it < niter; ++it) {
#pragma unroll
        for (int p = 0; p < 8; ++p) {
            asm volatile("s_waitcnt vmcnt(6)" ::: "memory");

            const int sa = ((p >> 2) << 2) | (((p >> 1) & 1) << 1);
            const int sb = sa + 1;
            const int mb = (p & 1) << 2;
            bf16x8 av[4], bv[NF];
#pragma unroll
            for (int m = 0; m < 4; ++m) {
                int row = wr * 128 + (mb + m) * 16 + fr;
                av[m] = *(const bf16x8*)((const char*)lds + sa * 16384 + row * 64 + ((kg * 16) ^ (((row >> 1) & 3) << 4)));
            }
#pragma unroll
            for (int n = 0; n < NF; ++n) {
                int row = wc * (NF * 16) + n * 16 + fr;
                bv[n] = *(const bf16x8*)((const char*)lds + sb * 16384 + row * 64 + ((kg * 16) ^ (((row >> 1) & 3) << 4)));
            }

            {
                int tau = 2 * it + 1 + ((p + 2) >> 2);
                if (tau > ntm1) tau = ntm1;                 // tail dummy
                const int kh = 1 - ((p >> 1) & 1);
                const u16* g0 = ((p & 1) ? bB : aB) + tau * 64 + kh * 32;
                u16* lb = ldsw + ((p + 6) & 7) * 8192;
                gload16(g0, lb);
                gload16(g0 + (size_t)128 * K, lb + 4096);
            }

            asm volatile("s_barrier" ::: "memory");
            asm volatile("s_waitcnt lgkmcnt(0)" ::: "memory");
            __builtin_amdgcn_sched_barrier(0);
            __builtin_amdgcn_s_setprio(1);
#pragma unroll
            for (int m = 0; m < 4; ++m)
#pragma unroll
                for (int n = 0; n < NF; ++n)
                    acc[mb + m][n] = __builtin_amdgcn_mfma_f32_16x16x32_bf16(av[m], bv[n], acc[mb + m][n], 0, 0, 0);
            __builtin_amdgcn_s_setprio(0);
            asm volatile("s_barrier" ::: "memory");
        }
    }

    const int fq = l >> 4;
    if (MODE == 0) {
        float* Sd = isSn ? g_Sn : g_Sp;
        const float* nb = isSn ? g_ng : g_np;
        float cmin[NF];
#pragma unroll
        for (int n = 0; n < NF; ++n) cmin[n] = 1e30f;

#pragma unroll
        for (int m = 0; m < 8; ++m) {
            const int row0 = i0 + wr * 128 + m * 16 + fq * 4;
            float rmin[4] = {1e30f, 1e30f, 1e30f, 1e30f};
#pragma unroll
            for (int n = 0; n < NF; ++n) {
                const int col = j0 + wc * 64 + n * 16 + fr;
                const float nbc = nb[col];
                f32x4 dm;
#pragma unroll
                for (int r = 0; r < 4; ++r) {
                    const int row = row0 + r;
                    float d2 = g_ng[row] + nbc - 2.f * acc[m][n][r];
                    float d = sqrtf(fmaxf(d2, 0.f));
                    if (isSn && col == row) d += 1000000.0f;
                    Sd[(size_t)row * 4096 + col] = d;
                    dm[r] = d;
                    rmin[r] = fminf(rmin[r], d);
                    cmin[n] = fminf(cmin[n], d);
                }
                if (isSn && !isDiag)   // mirror tile, coalesced dwordx4
                    *(f32x4*)&g_Sn[(size_t)col * 4096 + row0] = dm;
            }
            // row mins: reduce over fr (lanes 0..15 of each fq group)
#pragma unroll
            for (int r = 0; r < 4; ++r) {
                float v = rmin[r];
                v = fminf(v, __shfl_xor(v, 1, 64));
                v = fminf(v, __shfl_xor(v, 2, 64));
                v = fminf(v, __shfl_xor(v, 4, 64));
                v = fminf(v, __shfl_xor(v, 8, 64));
                if (fr == 0) atomicMinF(isSn ? &g_rminn[row0 + r] : &g_rminp[row0 + r], v);
            }
        }
        // col mins: reduce over fq groups
#pragma unroll
        for (int n = 0; n < NF; ++n) {
            float v = cmin[n];
            v = fminf(v, __shfl_xor(v, 16, 64));
            v = fminf(v, __shfl_xor(v, 32, 64));
            if (kg == 0) {
                const int col = j0 + wc * 64 + n * 16 + fr;
                atomicMinF(isSn ? &g_rminn[col] : &g_cminp[col], v);
            }
        }
    } else {
        float* Vout = g_Vall + (size_t)tsel * N_ * D_;
        float ssq = 0.f;
#pragma unroll
        for (int m = 0; m < 8; ++m)
#pragma unroll
            for (int n = 0; n < NF; ++n)
#pragma unroll
                for (int r = 0; r < 4; ++r) {
                    int row = i0 + wr * 128 + m * 16 + fq * 4 + r;
                    int col = j0 + wc * (NF * 16) + n * 16 + fr;
                    float v = acc[m][n][r];
                    Vout[(size_t)row * D_ + col] = v;
                    ssq += v * v;
                }
        asm volatile("s_waitcnt vmcnt(0)" ::: "memory");
        __syncthreads();
#pragma unroll
        for (int s = 32; s; s >>= 1) ssq += __shfl_down(ssq, s, 64);
        float* redf = (float*)lds;
        if (l == 0) redf[w] = ssq;
        __syncthreads();
        if (tid == 0) {
            float s = 0;
#pragma unroll
            for (int k = 0; k < 8; ++k) s += redf[k];
            g_part3[tsel * 256 + bid] = s;
        }
    }
}

// ---------------- per-row exp-sums (mins precomputed by S-GEMM atomics) -------
__global__ __launch_bounds__(256) void k_rowstat() {
    __shared__ float red[6][4];
    int i = blockIdx.x;
    float rd = fminf(g_rminp[i], g_rminn[i]);
    float rnn = g_rminn[i];
    const float4* rp4 = (const float4*)(g_Sp + (size_t)i * N_);
    const float4* rn4 = (const float4*)(g_Sn + (size_t)i * N_);
    float v[6] = {0, 0, 0, 0, 0, 0};
    for (int c = threadIdx.x; c < 1024; c += 256) {
        float4 a = rp4[c], b = rn4[c];
#pragma unroll
        for (int e = 0; e < 4; ++e) {
            float dp = (&a.x)[e], dn = (&b.x)[e];
            float ep = rd - dp;
            v[0] += __expf(ep * 50.f);
            v[1] += __expf(ep * 20.f);
            v[2] += __expf(ep * 5.f);
            float e2 = rd - dn, en = rnn - dn;
            v[0] += __expf(e2 * 50.f);
            v[1] += __expf(e2 * 20.f);
            v[2] += __expf(e2 * 5.f);
            v[3] += __expf(en * 50.f);
            v[4] += __expf(en * 20.f);
            v[5] += __expf(en * 5.f);
        }
    }
    int l = threadIdx.x & 63, w = threadIdx.x >> 6;
#pragma unroll
    for (int k = 0; k < 6; ++k)
#pragma unroll
        for (int s = 32; s; s >>= 1) v[k] += __shfl_down(v[k], s, 64);
    if (l == 0)
#pragma unroll
        for (int k = 0; k < 6; ++k) red[k][w] = v[k];
    __syncthreads();
    int t = threadIdx.x;
    if (t < 6) {
        float s = red[t][0] + red[t][1] + red[t][2] + red[t][3];
        if (t < 3) g_R[t * N_ + i] = rsqrtf(s);
        else g_Cn[(t - 3) * N_ + i] = rsqrtf(s);
    }
}

// ---------------- column exp-sums of d_pos ----------------
__global__ __launch_bounds__(256) void k_colexp() {
    int j = blockIdx.x * 256 + threadIdx.x;
    int ch = blockIdx.y;
    int i0 = ch * 512;
    float cm = g_cminp[j];
    float a0 = 0, a1 = 0, a2 = 0;
    for (int i = i0; i < i0 + 512; ++i) {
        float e = cm - g_Sp[(size_t)i * N_ + j];
        a0 += __expf(e * 50.f);
        a1 += __expf(e * 20.f);
        a2 += __expf(e * 5.f);
    }
    g_Cpart[(size_t)ch * (3 * N_) + 0 * N_ + j] = a0;
    g_Cpart[(size_t)ch * (3 * N_) + 1 * N_ + j] = a1;
    g_Cpart[(size_t)ch * (3 * N_) + 2 * N_ + j] = a2;
}
__global__ __launch_bounds__(256) void k_colreduce() {
    int idx = blockIdx.x * 256 + threadIdx.x;
    float s = 0;
#pragma unroll
    for (int ch = 0; ch < 8; ++ch) s += g_Cpart[(size_t)ch * (3 * N_) + idx];
    g_Cp[idx] = rsqrtf(s);
}

// ---------------- fused rowsumA + W generation (all 3 taus, one read) ----------
__global__ __launch_bounds__(256) void k_wfuse() {
    __shared__ float sp[4096];
    __shared__ float sn[4096];
    __shared__ float red[6][4];
    __shared__ float bc[6];
    int i = blockIdx.x;
    float rd = fminf(g_rminp[i], g_rminn[i]);
    const float4* rp4 = (const float4*)(g_Sp + (size_t)i * N_);
    const float4* rn4 = (const float4*)(g_Sn + (size_t)i * N_);
    for (int c = threadIdx.x; c < 1024; c += 256) {
        ((float4*)sp)[c] = rp4[c];
        ((float4*)sn)[c] = rn4[c];
    }
    __syncthreads();
    const float iR0 = g_R[i], iR1 = g_R[N_ + i], iR2 = g_R[2 * N_ + i];
    float v[6] = {0, 0, 0, 0, 0, 0};
    for (int j = threadIdx.x; j < 4096; j += 256) {
        float bp = 0.5f * (rd + g_cminp[j]) - sp[j];
        v[0] += __expf(bp * 50.f) * g_Cp[j];
        v[1] += __expf(bp * 20.f) * g_Cp[N_ + j];
        v[2] += __expf(bp * 5.f) * g_Cp[2 * N_ + j];
        float bn = 0.5f * (rd + g_rminn[j]) - sn[j];
        v[3] += __expf(bn * 50.f) * g_Cn[j];
        v[4] += __expf(bn * 20.f) * g_Cn[N_ + j];
        v[5] += __expf(bn * 5.f) * g_Cn[2 * N_ + j];
    }
    int l = threadIdx.x & 63, w = threadIdx.x >> 6;
#pragma unroll
    for (int k = 0; k < 6; ++k)
#pragma unroll
        for (int s = 32; s; s >>= 1) v[k] += __shfl_down(v[k], s, 64);
    if (l == 0)
#pragma unroll
        for (int k = 0; k < 6; ++k) red[k][w] = v[k];
    __syncthreads();
    if (threadIdx.x < 6) {
        int t = threadIdx.x;
        float s = red[t][0] + red[t][1] + red[t][2] + red[t][3];
        float iR = (t % 3 == 0) ? iR0 : ((t % 3 == 1) ? iR1 : iR2);
        bc[t] = s * iR;   // 0..2: spos_t ; 3..5: sneg_t
    }
    __syncthreads();
    const float sp0 = bc[0], sp1 = bc[1], sp2 = bc[2];
    const float sn0 = bc[3], sn1 = bc[4], sn2 = bc[5];
    for (int gq = threadIdx.x; gq < 512; gq += 256) {
        int j0 = gq * 8;
        u16 op[3][8], on[3][8];
#pragma unroll
        for (int e = 0; e < 8; ++e) {
            int j = j0 + e;
            float bp = 0.5f * (rd + g_cminp[j]) - sp[j];
            float bn = 0.5f * (rd + g_rminn[j]) - sn[j];
            op[0][e] = f2bf(__expf(bp * 50.f) * iR0 * g_Cp[j] * sn0);
            op[1][e] = f2bf(__expf(bp * 20.f) * iR1 * g_Cp[N_ + j] * sn1);
            op[2][e] = f2bf(__expf(bp * 5.f) * iR2 * g_Cp[2 * N_ + j] * sn2);
            on[0][e] = f2bf(-(__expf(bn * 50.f) * iR0 * g_Cn[j] * sp0));
            on[1][e] = f2bf(-(__expf(bn * 20.f) * iR1 * g_Cn[N_ + j] * sp1));
            on[2][e] = f2bf(-(__expf(bn * 5.f) * iR2 * g_Cn[2 * N_ + j] * sp2));
        }
#pragma unroll
        for (int t = 0; t < 3; ++t) {
            *(uint4*)&g_Wall[((size_t)t * N_ + i) * (2 * N_) + j0] = *(const uint4*)op[t];
            *(uint4*)&g_Wall[((size_t)t * N_ + i) * (2 * N_) + 4096 + j0] = *(const uint4*)on[t];
        }
    }
}

// ---------------- combine: scales from partials, final ssq ----------------
__global__ __launch_bounds__(256) void k_vcombine() {
    __shared__ float scsh[3];
    __shared__ float redm[4];
    for (int tau = 0; tau < 3; ++tau) {
        float v = g_part3[tau * 256 + threadIdx.x];
#pragma unroll
        for (int s = 32; s; s >>= 1) v += __shfl_down(v, s, 64);
        int l = threadIdx.x & 63, w = threadIdx.x >> 6;
        if (l == 0) redm[w] = v;
        __syncthreads();
        if (threadIdx.x == 0)
            scsh[tau] = rsqrtf((redm[0] + redm[1] + redm[2] + redm[3]) /
                               ((float)N_ * (float)D_) + 1e-8f);
        __syncthreads();
    }
    const float s0 = scsh[0], s1 = scsh[1], s2 = scsh[2];
    const float4* V0 = (const float4*)g_Vall;
    const float4* V1 = (const float4*)(g_Vall + (size_t)N_ * D_);
    const float4* V2 = (const float4*)(g_Vall + (size_t)2 * N_ * D_);
    const size_t n4 = (size_t)N_ * D_ / 4;
    float ssq = 0.f;
    for (size_t i = (size_t)blockIdx.x * 256 + threadIdx.x; i < n4; i += (size_t)1024 * 256) {
        float4 a = V0[i], b = V1[i], c = V2[i];
        float x = a.x * s0 + b.x * s1 + c.x * s2;
        float y = a.y * s0 + b.y * s1 + c.y * s2;
        float z = a.z * s0 + b.z * s1 + c.z * s2;
        float u = a.w * s0 + b.w * s1 + c.w * s2;
        ssq += x * x + y * y + z * z + u * u;
    }
    ssq = blockSum256(ssq);
    if (threadIdx.x == 0) g_part2[blockIdx.x] = ssq;
}

__global__ __launch_bounds__(256) void k_finalize(float* out) {
    float s = 0.f;
    for (int i = threadIdx.x; i < 1024; i += 256) s += g_part2[i];
    s = blockSum256(s);
    if (threadIdx.x == 0) {
        float m = s / ((float)N_ * (float)D_);
        out[0] = m / (m + 1e-8f);
    }
}

// ---------------- host orchestration ----------------
extern "C" void kernel_launch(void* const* d_in, const int* in_sizes, int n_in,
                              void* d_out, int out_size, void* d_ws, size_t ws_size,
                              hipStream_t stream) {
    const float* xg = (const float*)d_in[0];
    const float* xp = (const float*)d_in[1];
    float* out = (float*)d_out;

    k_mininit<<<48, 256, 0, stream>>>();
    k_convert_norm<<<N_, 256, 0, stream>>>(xg, 0);
    k_convert_norm<<<N_, 256, 0, stream>>>(xp, 1);
    k_transpose<<<dim3(D_ / 32, N_ / 32), dim3(32, 8), 0, stream>>>(0);
    k_transpose<<<dim3(D_ / 32, N_ / 32), dim3(32, 8), 0, stream>>>(1);

    k_gemm8<0><<<392, 512, 0, stream>>>(0);   // dist_pos + dist_neg (tri+mirror) + mins

    k_rowstat<<<N_, 256, 0, stream>>>();
    k_colexp<<<dim3(N_ / 256, 8), 256, 0, stream>>>();
    k_colreduce<<<3 * N_ / 256, 256, 0, stream>>>();
    k_wfuse<<<N_, 256, 0, stream>>>();

    for (int t = 0; t < 3; ++t)
        k_gemm8<1><<<256, 512, 0, stream>>>(t);   // -> g_Vall[t] + ssq partials

    k_vcombine<<<1024, 256, 0, stream>>>();
    k_finalize<<<1, 256, 0, stream>>>(out);
}

// Round 8
// 1109.478 us; speedup vs baseline: 1.6545x; 1.0153x over previous
//
#include <hip/hip_runtime.h>
#include <hip/hip_bf16.h>

typedef unsigned short u16;
typedef short bf16x8 __attribute__((ext_vector_type(8)));
typedef float f32x4 __attribute__((ext_vector_type(4)));

#define N_ 4096
#define D_ 3072

// ---------------- static device workspace ----------------
__device__ __align__(256) u16  g_Feat[(size_t)2 * N_ * D_];      // [Gb ; Pb]
__device__ __align__(256) u16  g_BT[(size_t)(D_ + 64) * 2 * N_]; // [3072(+64)][8192] = [PbT | GbT]
__device__ __align__(256) u16  g_Wall[(size_t)3 * N_ * 2 * N_];  // [tau][4096][8192] = [Wp | -Wn]
__device__ __align__(256) float g_Sp[(size_t)N_ * N_];           // dist_pos
__device__ __align__(256) float g_Sn[(size_t)N_ * N_];           // dist_neg (+diag mask)
__device__ __align__(256) float g_Vall[(size_t)3 * N_ * D_];     // V_tau, all taus
__device__ float g_ng[N_], g_np[N_];
__device__ float g_rminp[N_], g_rminn[N_], g_cminp[N_];          // via atomicMin in S-GEMM
__device__ float g_R [3 * N_];    // rsqrt(row exp-sums)
__device__ float g_Cp[3 * N_];    // rsqrt(col exp-sums, pos)
__device__ float g_Cn[3 * N_];    // rsqrt(col exp-sums, neg = row sums by symmetry)
__device__ float g_Cpart[8 * 3 * N_];
__device__ float g_part3[3 * 256];   // per-tau ssq partials from V-GEMM
__device__ float g_part2[1024];      // final ssq partials

// ---------------- helpers ----------------
__device__ __forceinline__ u16 f2bf(float f) {
    unsigned u = __float_as_uint(f);
    u += 0x7fffu + ((u >> 16) & 1u);
    return (u16)(u >> 16);
}

__device__ __forceinline__ float blockSum256(float v) {
    __shared__ float red[4];
#pragma unroll
    for (int s = 32; s; s >>= 1) v += __shfl_down(v, s, 64);
    int l = threadIdx.x & 63, w = threadIdx.x >> 6;
    if (l == 0) red[w] = v;
    __syncthreads();
    return red[0] + red[1] + red[2] + red[3];
}

__device__ __forceinline__ void gload16(const void* g, void* lds) {
    __builtin_amdgcn_global_load_lds(
        (const __attribute__((address_space(1))) void*)g,
        (__attribute__((address_space(3))) void*)lds, 16, 0, 0);
}

__device__ __forceinline__ void atomicMinF(float* p, float v) {
    atomicMin((unsigned int*)p, __float_as_uint(v));   // exact for v >= 0
}

// ---------------- convert fp32 -> bf16 + row sq-norms ----------------
__global__ __launch_bounds__(256) void k_convert_norm(const float* __restrict__ X, int sel) {
    u16* Xb = g_Feat + (size_t)sel * N_ * D_;
    float* nr = sel ? g_np : g_ng;
    int row = blockIdx.x;
    const float* xr = X + (size_t)row * D_;
    u16* xb = Xb + (size_t)row * D_;
    float s = 0.f;
    for (int c = threadIdx.x; c < D_; c += 256) {
        float v = xr[c];
        s += v * v;
        xb[c] = f2bf(v);
    }
    s = blockSum256(s);
    if (threadIdx.x == 0) nr[row] = s;
}

// ---------------- bf16 transpose -> g_BT[D_][8192] ----------------
__global__ __launch_bounds__(256) void k_transpose(int sel) {
    const u16* in = g_Feat + (size_t)sel * N_ * D_;
    const int colofs = sel ? 0 : 4096;
    __shared__ u16 t[32][33];
    int c0 = blockIdx.x * 32, r0 = blockIdx.y * 32;
    int tx = threadIdx.x, ty = threadIdx.y;
#pragma unroll
    for (int k = 0; k < 32; k += 8)
        t[ty + k][tx] = in[(size_t)(r0 + ty + k) * D_ + c0 + tx];
    __syncthreads();
#pragma unroll
    for (int k = 0; k < 32; k += 8)
        g_BT[(size_t)(c0 + ty + k) * (2 * N_) + colofs + r0 + tx] = t[tx][ty + k];
}

// ---------------- init min arrays ----------------
__global__ __launch_bounds__(256) void k_mininit() {
    int idx = blockIdx.x * 256 + threadIdx.x;   // 0..3*N_-1
    if (idx < N_) g_rminp[idx] = 1e30f;
    else if (idx < 2 * N_) g_rminn[idx - N_] = 1e30f;
    else g_cminp[idx - 2 * N_] = 1e30f;
}

// ---------------- 8-phase 256-row MFMA GEMM ----------------
// BM=256, BN=NF*64, BK=64; 8 waves (2Mx4N). LDS ring: 8 x 16KB half-slots
// (A_k0,B_k0,A_k1,B_k1 per 64-K tile). Swizzle: LDS(row,chunk) holds global
// (row, chunk ^ ((row>>1)&3)); pre-swizzled GLOBAL source (linear LDS dest),
// matching XOR on read -> uniform 2-way (free; conflicts=0 verified R4).
// Schedule: vmcnt(6) -> reads -> stage slot(p+6) -> barrier -> lgkmcnt(0)+
// sched_barrier -> setprio/MFMA -> barrier.
// R8 change: B-fragments (bv) read ONCE per k-step (even phase) and held in
// registers through the odd phase (same sa/sb; slot restaged 2 phases later,
// WAR-safe) -> 24 instead of 32 ds_read_b128 per K-tile per wave. LDS traffic
// was the binding resource (64KB/phase = 770cyc at 85B/cyc vs measured
// 1008-1368 cyc phases); this removes the 25-27% duplicated-B waste.
// MODE 0: S = G.G^T (triangle, mirrored) and G.P^T; K=3072, NF=4.
//   Grid 392 = 256 Sp blocks + 136 Sn upper-tri blocks. Epilogue: dist (+diag
//   mask), mirror store for off-diag Sn, atomicMin row/col mins.
// MODE 1: V_tau = W_tau.[P;G], K=8192, NF=3 -> g_Vall + ssq partials.
template <int MODE>
__global__ __launch_bounds__(512, 1) void k_gemm8(int tsel) {
    constexpr int NF = (MODE == 1) ? 3 : 4;
    constexpr int K  = (MODE == 1) ? 2 * N_ : D_;
    constexpr int nt = K >> 6;
    constexpr int niter = nt >> 1;
    constexpr int ntm1 = nt - 1;
    const u16* A = (MODE == 1) ? (g_Wall + (size_t)tsel * N_ * 2 * N_) : g_Feat;
    const u16* B = (MODE == 1) ? g_BT : g_Feat;

    __shared__ u16 lds[65536];   // 128 KiB

    const int nwg = gridDim.x;
    const int cpx = nwg >> 3;
    const int bid = blockIdx.x;
    const int swz = (bid & 7) * cpx + (bid >> 3);

    int i0, j0, jfeat;           // jfeat = row base within B matrix
    bool isSn = false, isDiag = false;
    if (MODE == 1) {
        const int by = swz >> 4, bx = swz & 15;
        i0 = by * 256; j0 = bx * (NF * 64); jfeat = j0;
    } else {
        if (swz < 256) {                       // Sp block
            const int by = swz >> 4, bx = swz & 15;
            i0 = by * 256; j0 = bx * 256; jfeat = 4096 + j0;
        } else {                               // Sn upper-triangle block
            int t = swz - 256, by = 0;
            while (t >= 16 - by) { t -= 16 - by; ++by; }
            const int bx = by + t;
            i0 = by * 256; j0 = bx * 256; jfeat = j0;
            isSn = true; isDiag = (bx == by);
        }
    }

    const int tid = threadIdx.x;
    const int l = tid & 63, w = tid >> 6;
    const int wr = w >> 2, wc = w & 3;
    const int fr = l & 15, kg = l >> 4;

    const int slrow = w * 16 + (l >> 2);
    const int scol = ((l & 3) ^ ((l >> 3) & 3)) * 8;    // inverse-swizzled source
    const u16* aB = A + (size_t)(i0 + slrow) * K + scol;
    const u16* bB = B + (size_t)(jfeat + slrow) * K + scol;
    u16* ldsw = lds + w * 512;

    f32x4 acc[8][NF] = {};

    // prologue: half-tile blocks H0..H5 (mat=h&1, khalf=(h>>1)&1, tile=h>>2)
#pragma unroll
    for (int h = 0; h < 6; ++h) {
        const int tau = h >> 2;
        const int kh = (h >> 1) & 1;
        const u16* g0 = ((h & 1) ? bB : aB) + tau * 64 + kh * 32;
        u16* lb = ldsw + h * 8192;
        gload16(g0, lb);
        gload16(g0 + (size_t)128 * K, lb + 4096);
    }
    asm volatile("s_waitcnt vmcnt(6)" ::: "memory");
    asm volatile("s_barrier" ::: "memory");

    for (int it = 0; it < niter; ++it) {
        bf16x8 bv[NF];   // held across each phase pair (read in even phase only)
#pragma unroll
        for (int p = 0; p < 8; ++p) {
            asm volatile("s_waitcnt vmcnt(6)" ::: "memory");

            const int sa = ((p >> 2) << 2) | (((p >> 1) & 1) << 1);
            const int sb = sa + 1;
            const int mb = (p & 1) << 2;
            bf16x8 av[4];
#pragma unroll
            for (int m = 0; m < 4; ++m) {
                int row = wr * 128 + (mb + m) * 16 + fr;
                av[m] = *(const bf16x8*)((const char*)lds + sa * 16384 + row * 64 + ((kg * 16) ^ (((row >> 1) & 3) << 4)));
            }
            if ((p & 1) == 0) {   // B frags once per k-step, reused in odd phase
#pragma unroll
                for (int n = 0; n < NF; ++n) {
                    int row = wc * (NF * 16) + n * 16 + fr;
                    bv[n] = *(const bf16x8*)((const char*)lds + sb * 16384 + row * 64 + ((kg * 16) ^ (((row >> 1) & 3) << 4)));
                }
            }

            {
                int tau = 2 * it + 1 + ((p + 2) >> 2);
                if (tau > ntm1) tau = ntm1;                 // tail dummy
                const int kh = 1 - ((p >> 1) & 1);
                const u16* g0 = ((p & 1) ? bB : aB) + tau * 64 + kh * 32;
                u16* lb = ldsw + ((p + 6) & 7) * 8192;
                gload16(g0, lb);
                gload16(g0 + (size_t)128 * K, lb + 4096);
            }

            asm volatile("s_barrier" ::: "memory");
            asm volatile("s_waitcnt lgkmcnt(0)" ::: "memory");
            __builtin_amdgcn_sched_barrier(0);
            __builtin_amdgcn_s_setprio(1);
#pragma unroll
            for (int m = 0; m < 4; ++m)
#pragma unroll
                for (int n = 0; n < NF; ++n)
                    acc[mb + m][n] = __builtin_amdgcn_mfma_f32_16x16x32_bf16(av[m], bv[n], acc[mb + m][n], 0, 0, 0);
            __builtin_amdgcn_s_setprio(0);
            asm volatile("s_barrier" ::: "memory");
        }
    }

    const int fq = l >> 4;
    if (MODE == 0) {
        float* Sd = isSn ? g_Sn : g_Sp;
        const float* nb = isSn ? g_ng : g_np;
        float cmin[NF];
#pragma unroll
        for (int n = 0; n < NF; ++n) cmin[n] = 1e30f;

#pragma unroll
        for (int m = 0; m < 8; ++m) {
            const int row0 = i0 + wr * 128 + m * 16 + fq * 4;
            float rmin[4] = {1e30f, 1e30f, 1e30f, 1e30f};
#pragma unroll
            for (int n = 0; n < NF; ++n) {
                const int col = j0 + wc * 64 + n * 16 + fr;
                const float nbc = nb[col];
                f32x4 dm;
#pragma unroll
                for (int r = 0; r < 4; ++r) {
                    const int row = row0 + r;
                    float d2 = g_ng[row] + nbc - 2.f * acc[m][n][r];
                    float d = sqrtf(fmaxf(d2, 0.f));
                    if (isSn && col == row) d += 1000000.0f;
                    Sd[(size_t)row * 4096 + col] = d;
                    dm[r] = d;
                    rmin[r] = fminf(rmin[r], d);
                    cmin[n] = fminf(cmin[n], d);
                }
                if (isSn && !isDiag)   // mirror tile, line-coalesced across fq
                    *(f32x4*)&g_Sn[(size_t)col * 4096 + row0] = dm;
            }
#pragma unroll
            for (int r = 0; r < 4; ++r) {
                float v = rmin[r];
                v = fminf(v, __shfl_xor(v, 1, 64));
                v = fminf(v, __shfl_xor(v, 2, 64));
                v = fminf(v, __shfl_xor(v, 4, 64));
                v = fminf(v, __shfl_xor(v, 8, 64));
                if (fr == 0) atomicMinF(isSn ? &g_rminn[row0 + r] : &g_rminp[row0 + r], v);
            }
        }
#pragma unroll
        for (int n = 0; n < NF; ++n) {
            float v = cmin[n];
            v = fminf(v, __shfl_xor(v, 16, 64));
            v = fminf(v, __shfl_xor(v, 32, 64));
            if (kg == 0) {
                const int col = j0 + wc * 64 + n * 16 + fr;
                atomicMinF(isSn ? &g_rminn[col] : &g_cminp[col], v);
            }
        }
    } else {
        float* Vout = g_Vall + (size_t)tsel * N_ * D_;
        float ssq = 0.f;
#pragma unroll
        for (int m = 0; m < 8; ++m)
#pragma unroll
            for (int n = 0; n < NF; ++n)
#pragma unroll
                for (int r = 0; r < 4; ++r) {
                    int row = i0 + wr * 128 + m * 16 + fq * 4 + r;
                    int col = j0 + wc * (NF * 16) + n * 16 + fr;
                    float v = acc[m][n][r];
                    Vout[(size_t)row * D_ + col] = v;
                    ssq += v * v;
                }
        asm volatile("s_waitcnt vmcnt(0)" ::: "memory");
        __syncthreads();
#pragma unroll
        for (int s = 32; s; s >>= 1) ssq += __shfl_down(ssq, s, 64);
        float* redf = (float*)lds;
        if (l == 0) redf[w] = ssq;
        __syncthreads();
        if (tid == 0) {
            float s = 0;
#pragma unroll
            for (int k = 0; k < 8; ++k) s += redf[k];
            g_part3[tsel * 256 + bid] = s;
        }
    }
}

// ---------------- per-row exp-sums (mins precomputed by S-GEMM atomics) -------
__global__ __launch_bounds__(256) void k_rowstat() {
    __shared__ float red[6][4];
    int i = blockIdx.x;
    float rd = fminf(g_rminp[i], g_rminn[i]);
    float rnn = g_rminn[i];
    const float4* rp4 = (const float4*)(g_Sp + (size_t)i * N_);
    const float4* rn4 = (const float4*)(g_Sn + (size_t)i * N_);
    float v[6] = {0, 0, 0, 0, 0, 0};
    for (int c = threadIdx.x; c < 1024; c += 256) {
        float4 a = rp4[c], b = rn4[c];
#pragma unroll
        for (int e = 0; e < 4; ++e) {
            float dp = (&a.x)[e], dn = (&b.x)[e];
            float ep = rd - dp;
            v[0] += __expf(ep * 50.f);
            v[1] += __expf(ep * 20.f);
            v[2] += __expf(ep * 5.f);
            float e2 = rd - dn, en = rnn - dn;
            v[0] += __expf(e2 * 50.f);
            v[1] += __expf(e2 * 20.f);
            v[2] += __expf(e2 * 5.f);
            v[3] += __expf(en * 50.f);
            v[4] += __expf(en * 20.f);
            v[5] += __expf(en * 5.f);
        }
    }
    int l = threadIdx.x & 63, w = threadIdx.x >> 6;
#pragma unroll
    for (int k = 0; k < 6; ++k)
#pragma unroll
        for (int s = 32; s; s >>= 1) v[k] += __shfl_down(v[k], s, 64);
    if (l == 0)
#pragma unroll
        for (int k = 0; k < 6; ++k) red[k][w] = v[k];
    __syncthreads();
    int t = threadIdx.x;
    if (t < 6) {
        float s = red[t][0] + red[t][1] + red[t][2] + red[t][3];
        if (t < 3) g_R[t * N_ + i] = rsqrtf(s);
        else g_Cn[(t - 3) * N_ + i] = rsqrtf(s);
    }
}

// ---------------- column exp-sums of d_pos ----------------
__global__ __launch_bounds__(256) void k_colexp() {
    int j = blockIdx.x * 256 + threadIdx.x;
    int ch = blockIdx.y;
    int i0 = ch * 512;
    float cm = g_cminp[j];
    float a0 = 0, a1 = 0, a2 = 0;
    for (int i = i0; i < i0 + 512; ++i) {
        float e = cm - g_Sp[(size_t)i * N_ + j];
        a0 += __expf(e * 50.f);
        a1 += __expf(e * 20.f);
        a2 += __expf(e * 5.f);
    }
    g_Cpart[(size_t)ch * (3 * N_) + 0 * N_ + j] = a0;
    g_Cpart[(size_t)ch * (3 * N_) + 1 * N_ + j] = a1;
    g_Cpart[(size_t)ch * (3 * N_) + 2 * N_ + j] = a2;
}
__global__ __launch_bounds__(256) void k_colreduce() {
    int idx = blockIdx.x * 256 + threadIdx.x;
    float s = 0;
#pragma unroll
    for (int ch = 0; ch < 8; ++ch) s += g_Cpart[(size_t)ch * (3 * N_) + idx];
    g_Cp[idx] = rsqrtf(s);
}

// ---------------- fused rowsumA + W generation (all 3 taus, one read) ----------
__global__ __launch_bounds__(256) void k_wfuse() {
    __shared__ float sp[4096];
    __shared__ float sn[4096];
    __shared__ float red[6][4];
    __shared__ float bc[6];
    int i = blockIdx.x;
    float rd = fminf(g_rminp[i], g_rminn[i]);
    const float4* rp4 = (const float4*)(g_Sp + (size_t)i * N_);
    const float4* rn4 = (const float4*)(g_Sn + (size_t)i * N_);
    for (int c = threadIdx.x; c < 1024; c += 256) {
        ((float4*)sp)[c] = rp4[c];
        ((float4*)sn)[c] = rn4[c];
    }
    __syncthreads();
    const float iR0 = g_R[i], iR1 = g_R[N_ + i], iR2 = g_R[2 * N_ + i];
    float v[6] = {0, 0, 0, 0, 0, 0};
    for (int j = threadIdx.x; j < 4096; j += 256) {
        float bp = 0.5f * (rd + g_cminp[j]) - sp[j];
        v[0] += __expf(bp * 50.f) * g_Cp[j];
        v[1] += __expf(bp * 20.f) * g_Cp[N_ + j];
        v[2] += __expf(bp * 5.f) * g_Cp[2 * N_ + j];
        float bn = 0.5f * (rd + g_rminn[j]) - sn[j];
        v[3] += __expf(bn * 50.f) * g_Cn[j];
        v[4] += __expf(bn * 20.f) * g_Cn[N_ + j];
        v[5] += __expf(bn * 5.f) * g_Cn[2 * N_ + j];
    }
    int l = threadIdx.x & 63, w = threadIdx.x >> 6;
#pragma unroll
    for (int k = 0; k < 6; ++k)
#pragma unroll
        for (int s = 32; s; s >>= 1) v[k] += __shfl_down(v[k], s, 64);
    if (l == 0)
#pragma unroll
        for (int k = 0; k < 6; ++k) red[k][w] = v[k];
    __syncthreads();
    if (threadIdx.x < 6) {
        int t = threadIdx.x;
        float s = red[t][0] + red[t][1] + red[t][2] + red[t][3];
        float iR = (t % 3 == 0) ? iR0 : ((t % 3 == 1) ? iR1 : iR2);
        bc[t] = s * iR;   // 0..2: spos_t ; 3..5: sneg_t
    }
    __syncthreads();
    const float sp0 = bc[0], sp1 = bc[1], sp2 = bc[2];
    const float sn0 = bc[3], sn1 = bc[4], sn2 = bc[5];
    for (int gq = threadIdx.x; gq < 512; gq += 256) {
        int j0 = gq * 8;
        u16 op[3][8], on[3][8];
#pragma unroll
        for (int e = 0; e < 8; ++e) {
            int j = j0 + e;
            float bp = 0.5f * (rd + g_cminp[j]) - sp[j];
            float bn = 0.5f * (rd + g_rminn[j]) - sn[j];
            op[0][e] = f2bf(__expf(bp * 50.f) * iR0 * g_Cp[j] * sn0);
            op[1][e] = f2bf(__expf(bp * 20.f) * iR1 * g_Cp[N_ + j] * sn1);
            op[2][e] = f2bf(__expf(bp * 5.f) * iR2 * g_Cp[2 * N_ + j] * sn2);
            on[0][e] = f2bf(-(__expf(bn * 50.f) * iR0 * g_Cn[j] * sp0));
            on[1][e] = f2bf(-(__expf(bn * 20.f) * iR1 * g_Cn[N_ + j] * sp1));
            on[2][e] = f2bf(-(__expf(bn * 5.f) * iR2 * g_Cn[2 * N_ + j] * sp2));
        }
#pragma unroll
        for (int t = 0; t < 3; ++t) {
            *(uint4*)&g_Wall[((size_t)t * N_ + i) * (2 * N_) + j0] = *(const uint4*)op[t];
            *(uint4*)&g_Wall[((size_t)t * N_ + i) * (2 * N_) + 4096 + j0] = *(const uint4*)on[t];
        }
    }
}

// ---------------- combine: scales from partials, final ssq ----------------
__global__ __launch_bounds__(256) void k_vcombine() {
    __shared__ float scsh[3];
    __shared__ float redm[4];
    for (int tau = 0; tau < 3; ++tau) {
        float v = g_part3[tau * 256 + threadIdx.x];
#pragma unroll
        for (int s = 32; s; s >>= 1) v += __shfl_down(v, s, 64);
        int l = threadIdx.x & 63, w = threadIdx.x >> 6;
        if (l == 0) redm[w] = v;
        __syncthreads();
        if (threadIdx.x == 0)
            scsh[tau] = rsqrtf((redm[0] + redm[1] + redm[2] + redm[3]) /
                               ((float)N_ * (float)D_) + 1e-8f);
        __syncthreads();
    }
    const float s0 = scsh[0], s1 = scsh[1], s2 = scsh[2];
    const float4* V0 = (const float4*)g_Vall;
    const float4* V1 = (const float4*)(g_Vall + (size_t)N_ * D_);
    const float4* V2 = (const float4*)(g_Vall + (size_t)2 * N_ * D_);
    const size_t n4 = (size_t)N_ * D_ / 4;
    float ssq = 0.f;
    for (size_t i = (size_t)blockIdx.x * 256 + threadIdx.x; i < n4; i += (size_t)1024 * 256) {
        float4 a = V0[i], b = V1[i], c = V2[i];
        float x = a.x * s0 + b.x * s1 + c.x * s2;
        float y = a.y * s0 + b.y * s1 + c.y * s2;
        float z = a.z * s0 + b.z * s1 + c.z * s2;
        float u = a.w * s0 + b.w * s1 + c.w * s2;
        ssq += x * x + y * y + z * z + u * u;
    }
    ssq = blockSum256(ssq);
    if (threadIdx.x == 0) g_part2[blockIdx.x] = ssq;
}

__global__ __launch_bounds__(256) void k_finalize(float* out) {
    float s = 0.f;
    for (int i = threadIdx.x; i < 1024; i += 256) s += g_part2[i];
    s = blockSum256(s);
    if (threadIdx.x == 0) {
        float m = s / ((float)N_ * (float)D_);
        out[0] = m / (m + 1e-8f);
    }
}

// ---------------- host orchestration ----------------
extern "C" void kernel_launch(void* const* d_in, const int* in_sizes, int n_in,
                              void* d_out, int out_size, void* d_ws, size_t ws_size,
                              hipStream_t stream) {
    const float* xg = (const float*)d_in[0];
    const float* xp = (const float*)d_in[1];
    float* out = (float*)d_out;

    k_mininit<<<48, 256, 0, stream>>>();
    k_convert_norm<<<N_, 256, 0, stream>>>(xg, 0);
    k_convert_norm<<<N_, 256, 0, stream>>>(xp, 1);
    k_transpose<<<dim3(D_ / 32, N_ / 32), dim3(32, 8), 0, stream>>>(0);
    k_transpose<<<dim3(D_ / 32, N_ / 32), dim3(32, 8), 0, stream>>>(1);

    k_gemm8<0><<<392, 512, 0, stream>>>(0);   // dist_pos + dist_neg (tri+mirror) + mins

    k_rowstat<<<N_, 256, 0, stream>>>();
    k_colexp<<<dim3(N_ / 256, 8), 256, 0, stream>>>();
    k_colreduce<<<3 * N_ / 256, 256, 0, stream>>>();
    k_wfuse<<<N_, 256, 0, stream>>>();

    for (int t = 0; t < 3; ++t)
        k_gemm8<1><<<256, 512, 0, stream>>>(t);   // -> g_Vall[t] + ssq partials

    k_vcombine<<<1024, 256, 0, stream>>>();
    k_finalize<<<1, 256, 0, stream>>>(out);
}